// Round 1
// baseline (501.244 us; speedup 1.0000x reference)
//
#include <hip/hip_runtime.h>
#include <hip/hip_bf16.h>

// Problem dims (fixed by the harness setup_inputs):
constexpr int B  = 128;
constexpr int LQ = 128;
constexpr int LS = 256;
constexpr int D  = 1024;
constexpr int SD = 256;   // sim_dim
constexpr float EPS = 1e-8f;

// ---------------- reduction helpers ----------------
__device__ inline float warp_reduce_sum(float v) {
#pragma unroll
    for (int off = 32; off; off >>= 1) v += __shfl_xor(v, off);
    return v;
}
__device__ inline float warp_reduce_max(float v) {
#pragma unroll
    for (int off = 32; off; off >>= 1) v = fmaxf(v, __shfl_xor(v, off));
    return v;
}

// =====================================================================
// Kernel 1: attn_raw[b,s,q] = leakyrelu( sum_d context[b,s,d] * (query[b,q,d]*matrix[b,q,d]) )
// NT GEMM per batch: M=LS (s), N=LQ (q), K=D. Tile 64x64, KC=32, 256 thr, 4x4/thread.
// =====================================================================
__global__ __launch_bounds__(256) void gemm1_kernel(
    const float* __restrict__ ctx, const float* __restrict__ query,
    const float* __restrict__ mat, float* __restrict__ attn)
{
    const int b  = blockIdx.z;
    const int m0 = blockIdx.y * 64;   // s
    const int n0 = blockIdx.x * 64;   // q
    __shared__ float As[32][64];
    __shared__ float Bs[32][64];
    const int t  = threadIdx.x;
    const int tx = t & 15, ty = t >> 4;
    const int lr = t >> 3;          // 0..31
    const int lk = (t & 7) * 4;     // 0..28

    const float* Ab = ctx   + (size_t)b * LS * D;
    const float* Qb = query + (size_t)b * LQ * D;
    const float* Mb = mat   + (size_t)b * LQ * D;

    float acc[4][4] = {};

    for (int k0 = 0; k0 < D; k0 += 32) {
#pragma unroll
        for (int half = 0; half < 2; ++half) {
            const int r = lr + half * 32;
            float4 av = *(const float4*)(Ab + (size_t)(m0 + r) * D + k0 + lk);
            As[lk + 0][r] = av.x; As[lk + 1][r] = av.y;
            As[lk + 2][r] = av.z; As[lk + 3][r] = av.w;
            float4 qv = *(const float4*)(Qb + (size_t)(n0 + r) * D + k0 + lk);
            float4 mv = *(const float4*)(Mb + (size_t)(n0 + r) * D + k0 + lk);
            Bs[lk + 0][r] = qv.x * mv.x; Bs[lk + 1][r] = qv.y * mv.y;
            Bs[lk + 2][r] = qv.z * mv.z; Bs[lk + 3][r] = qv.w * mv.w;
        }
        __syncthreads();
#pragma unroll
        for (int kk = 0; kk < 32; ++kk) {
            float4 a4 = *(const float4*)&As[kk][ty * 4];
            float4 b4 = *(const float4*)&Bs[kk][tx * 4];
            const float* ap = (const float*)&a4;
            const float* bp = (const float*)&b4;
#pragma unroll
            for (int i = 0; i < 4; ++i)
#pragma unroll
                for (int j = 0; j < 4; ++j) acc[i][j] += ap[i] * bp[j];
        }
        __syncthreads();
    }
#pragma unroll
    for (int i = 0; i < 4; ++i) {
        float4 o;
        float* op = (float*)&o;
#pragma unroll
        for (int j = 0; j < 4; ++j) {
            float v = acc[i][j];
            op[j] = v >= 0.f ? v : 0.1f * v;
        }
        *(float4*)&attn[((size_t)b * LS + m0 + ty * 4 + i) * LQ + n0 + tx * 4] = o;
    }
}

// =====================================================================
// Kernel 2: l2norm rows over q (length LQ=128). One 64-thread wave per (b,s) row.
// =====================================================================
__global__ __launch_bounds__(64) void rownorm_kernel(float* __restrict__ attn)
{
    const size_t row = blockIdx.x;         // b*LS + s
    float* p = attn + row * LQ;
    const int t = threadIdx.x;
    float v0 = p[t], v1 = p[t + 64];
    float ss = warp_reduce_sum(v0 * v0 + v1 * v1);
    float inv = 1.0f / (sqrtf(ss) + EPS);
    p[t]      = v0 * inv;
    p[t + 64] = v1 * inv;
}

// =====================================================================
// Kernel 3: softmax over s (scale by smooth), transposed write.
// attnT[b,q,s] = softmax_s( attn[b,s,q] * smooth ). 256 threads per (b,q).
// =====================================================================
__global__ __launch_bounds__(256) void softmax_kernel(
    const float* __restrict__ attn, float* __restrict__ attnT,
    const int* __restrict__ smooth_p)
{
    const int b = blockIdx.x >> 7;
    const int q = blockIdx.x & (LQ - 1);
    const int s = threadIdx.x;
    const float sm = (float)(*smooth_p);
    __shared__ float sred[4];

    float v = attn[((size_t)b * LS + s) * LQ + q] * sm;

    float wmax = warp_reduce_max(v);
    if ((s & 63) == 0) sred[s >> 6] = wmax;
    __syncthreads();
    float mx = fmaxf(fmaxf(sred[0], sred[1]), fmaxf(sred[2], sred[3]));
    __syncthreads();

    float e = __expf(v - mx);
    float wsum = warp_reduce_sum(e);
    if ((s & 63) == 0) sred[s >> 6] = wsum;
    __syncthreads();
    float total = sred[0] + sred[1] + sred[2] + sred[3];

    attnT[((size_t)b * LQ + q) * LS + s] = e / total;
}

// =====================================================================
// Kernel 4: wcontext[b,q,d] = sum_s attnT[b,q,s] * context[b,s,d]
// NN GEMM: M=LQ (q), N=D (d), K=LS (s). Tile 64x64, KC=32.
// =====================================================================
__global__ __launch_bounds__(256) void gemm2_kernel(
    const float* __restrict__ attnT, const float* __restrict__ ctx,
    float* __restrict__ wctx)
{
    const int b  = blockIdx.z;
    const int m0 = blockIdx.y * 64;   // q
    const int n0 = blockIdx.x * 64;   // d
    __shared__ float As[32][64];
    __shared__ float Bs[32][64];
    const int t  = threadIdx.x;
    const int tx = t & 15, ty = t >> 4;

    const float* Ab = attnT + (size_t)b * LQ * LS;
    const float* Bb = ctx   + (size_t)b * LS * D;

    float acc[4][4] = {};

    const int lr = t >> 3;          // A: 0..31
    const int lk = (t & 7) * 4;
    const int kr = t >> 4;          // B: 0..15
    const int nq = (t & 15) * 4;

    for (int k0 = 0; k0 < LS; k0 += 32) {
#pragma unroll
        for (int half = 0; half < 2; ++half) {
            const int r = lr + half * 32;
            float4 av = *(const float4*)(Ab + (size_t)(m0 + r) * LS + k0 + lk);
            As[lk + 0][r] = av.x; As[lk + 1][r] = av.y;
            As[lk + 2][r] = av.z; As[lk + 3][r] = av.w;
            const int kk2 = kr + half * 16;
            float4 bv = *(const float4*)(Bb + (size_t)(k0 + kk2) * D + n0 + nq);
            *(float4*)&Bs[kk2][nq] = bv;
        }
        __syncthreads();
#pragma unroll
        for (int kk = 0; kk < 32; ++kk) {
            float4 a4 = *(const float4*)&As[kk][ty * 4];
            float4 b4 = *(const float4*)&Bs[kk][tx * 4];
            const float* ap = (const float*)&a4;
            const float* bp = (const float*)&b4;
#pragma unroll
            for (int i = 0; i < 4; ++i)
#pragma unroll
                for (int j = 0; j < 4; ++j) acc[i][j] += ap[i] * bp[j];
        }
        __syncthreads();
    }
#pragma unroll
    for (int i = 0; i < 4; ++i) {
        float4 o;
        float* op = (float*)&o;
#pragma unroll
        for (int j = 0; j < 4; ++j) op[j] = acc[i][j];
        *(float4*)&wctx[((size_t)b * LQ + m0 + ty * 4 + i) * D + n0 + tx * 4] = o;
    }
}

// =====================================================================
// Kernel 5: sr[b,q,d] = (query[b,q,d] - wcontext_l2normed[b,q,d])^2  (in place over wctx)
// One 256-thread block per (b,q) row; float4 per thread.
// =====================================================================
__global__ __launch_bounds__(256) void prep_kernel(
    float* __restrict__ wctx, const float* __restrict__ query)
{
    const size_t row = blockIdx.x;       // b*LQ + q
    const int t = threadIdx.x;
    __shared__ float sred[4];

    float4 w = *(const float4*)&wctx[row * D + t * 4];
    float ss = w.x * w.x + w.y * w.y + w.z * w.z + w.w * w.w;
    ss = warp_reduce_sum(ss);
    if ((t & 63) == 0) sred[t >> 6] = ss;
    __syncthreads();
    float tot = sred[0] + sred[1] + sred[2] + sred[3];
    float inv = 1.0f / (sqrtf(tot) + EPS);

    float4 qv = *(const float4*)&query[row * D + t * 4];
    float4 o;
    o.x = qv.x - w.x * inv; o.x *= o.x;
    o.y = qv.y - w.y * inv; o.y *= o.y;
    o.z = qv.z - w.z * inv; o.z *= o.z;
    o.w = qv.w - w.w * inv; o.w *= o.w;
    *(float4*)&wctx[row * D + t * 4] = o;
}

// =====================================================================
// Kernel 6: tmp[b,q,k] = sum_d sr[b,q,d] * W[k,d] + bias[k]
// NT GEMM: M=LQ, N=SD, K=D. Tile 64x64, KC=32.
// =====================================================================
__global__ __launch_bounds__(256) void gemm3_kernel(
    const float* __restrict__ sr, const float* __restrict__ W,
    const float* __restrict__ bias, float* __restrict__ tmp)
{
    const int b  = blockIdx.z;
    const int m0 = blockIdx.y * 64;   // q
    const int n0 = blockIdx.x * 64;   // k_sim
    __shared__ float As[32][64];
    __shared__ float Bs[32][64];
    const int t  = threadIdx.x;
    const int tx = t & 15, ty = t >> 4;
    const int lr = t >> 3;
    const int lk = (t & 7) * 4;

    const float* Ab = sr + (size_t)b * LQ * D;

    float acc[4][4] = {};

    for (int k0 = 0; k0 < D; k0 += 32) {
#pragma unroll
        for (int half = 0; half < 2; ++half) {
            const int r = lr + half * 32;
            float4 av = *(const float4*)(Ab + (size_t)(m0 + r) * D + k0 + lk);
            As[lk + 0][r] = av.x; As[lk + 1][r] = av.y;
            As[lk + 2][r] = av.z; As[lk + 3][r] = av.w;
            float4 bv = *(const float4*)(W + (size_t)(n0 + r) * D + k0 + lk);
            Bs[lk + 0][r] = bv.x; Bs[lk + 1][r] = bv.y;
            Bs[lk + 2][r] = bv.z; Bs[lk + 3][r] = bv.w;
        }
        __syncthreads();
#pragma unroll
        for (int kk = 0; kk < 32; ++kk) {
            float4 a4 = *(const float4*)&As[kk][ty * 4];
            float4 b4 = *(const float4*)&Bs[kk][tx * 4];
            const float* ap = (const float*)&a4;
            const float* bp = (const float*)&b4;
#pragma unroll
            for (int i = 0; i < 4; ++i)
#pragma unroll
                for (int j = 0; j < 4; ++j) acc[i][j] += ap[i] * bp[j];
        }
        __syncthreads();
    }
#pragma unroll
    for (int i = 0; i < 4; ++i) {
        float4 o;
        float* op = (float*)&o;
#pragma unroll
        for (int j = 0; j < 4; ++j) op[j] = acc[i][j] + bias[n0 + tx * 4 + j];
        *(float4*)&tmp[((size_t)b * LQ + m0 + ty * 4 + i) * SD + n0 + tx * 4] = o;
    }
}

// =====================================================================
// Kernel 7: out[b,q,k] = tmp[b,q,k] / (||tmp[b,q,:]|| + eps). 256 thr per row.
// =====================================================================
__global__ __launch_bounds__(256) void finalnorm_kernel(
    const float* __restrict__ tmp, float* __restrict__ out)
{
    const size_t row = blockIdx.x;       // b*LQ + q
    const int t = threadIdx.x;
    __shared__ float sred[4];

    float v = tmp[row * SD + t];
    float ss = warp_reduce_sum(v * v);
    if ((t & 63) == 0) sred[t >> 6] = ss;
    __syncthreads();
    float tot = sred[0] + sred[1] + sred[2] + sred[3];
    float inv = 1.0f / (sqrtf(tot) + EPS);
    out[row * SD + t] = v * inv;
}

// =====================================================================
extern "C" void kernel_launch(void* const* d_in, const int* in_sizes, int n_in,
                              void* d_out, int out_size, void* d_ws, size_t ws_size,
                              hipStream_t stream)
{
    const float* query  = (const float*)d_in[0];
    const float* ctx    = (const float*)d_in[1];
    const float* mat    = (const float*)d_in[2];
    const float* W      = (const float*)d_in[3];
    const float* bias   = (const float*)d_in[4];
    const int*   smooth = (const int*)d_in[5];
    float* out = (float*)d_out;

    float* ws    = (float*)d_ws;
    float* attn  = ws;                               // B*LS*LQ   (16 MB)
    float* attnT = ws + (size_t)B * LS * LQ;         // B*LQ*LS   (16 MB)
    float* wctx  = attnT + (size_t)B * LQ * LS;      // B*LQ*D    (64 MB)
    float* tmp   = attn;                             // reuse: B*LQ*SD (16 MB), attn dead after softmax

    // 1) attn_raw = leakyrelu(context . (query*matrix)^T)
    gemm1_kernel<<<dim3(LQ / 64, LS / 64, B), 256, 0, stream>>>(ctx, query, mat, attn);
    // 2) l2norm over q
    rownorm_kernel<<<dim3(B * LS), 64, 0, stream>>>(attn);
    // 3) softmax over s (with transpose)
    softmax_kernel<<<dim3(B * LQ), 256, 0, stream>>>(attn, attnT, smooth);
    // 4) wcontext = attnT . context
    gemm2_kernel<<<dim3(D / 64, LQ / 64, B), 256, 0, stream>>>(attnT, ctx, wctx);
    // 5) sr = (query - l2norm(wcontext))^2   (in place)
    prep_kernel<<<dim3(B * LQ), 256, 0, stream>>>(wctx, query);
    // 6) tmp = sr . W^T + b
    gemm3_kernel<<<dim3(SD / 64, LQ / 64, B), 256, 0, stream>>>(wctx, W, bias, tmp);
    // 7) out = l2norm(tmp)
    finalnorm_kernel<<<dim3(B * LQ), 256, 0, stream>>>(tmp, out);
}

// Round 2
// 275.781 us; speedup vs baseline: 1.8175x; 1.8175x over previous
//
#include <hip/hip_runtime.h>
#include <hip/hip_bf16.h>

constexpr int B  = 128;
constexpr int LQ = 128;
constexpr int LS = 256;
constexpr int D  = 1024;
constexpr int SD = 256;
constexpr float EPS = 1e-8f;

typedef __attribute__((ext_vector_type(8))) __bf16 bf16x8;
typedef __attribute__((ext_vector_type(4))) float f32x4;

__device__ inline ushort f2bf(float f) {
    union { float f; uint u; } v{f};
    uint r = v.u + 0x7fffu + ((v.u >> 16) & 1u);   // RNE
    return (ushort)(r >> 16);
}
__device__ inline float bf2f(ushort u) {
    union { uint u; float f; } v{(uint)u << 16};
    return v.f;
}
__device__ inline uint4 pack8(float4 a, float4 b) {
    union { ushort us[8]; uint4 u4; } r;
    r.us[0]=f2bf(a.x); r.us[1]=f2bf(a.y); r.us[2]=f2bf(a.z); r.us[3]=f2bf(a.w);
    r.us[4]=f2bf(b.x); r.us[5]=f2bf(b.y); r.us[6]=f2bf(b.z); r.us[7]=f2bf(b.w);
    return r.u4;
}
// LDS rows are 64 bf16 = 128 B; XOR-swizzle bank fix (G4 / m214 pattern)
__device__ inline int swz(int row, int kbyte) {
    return row * 128 + (kbyte ^ ((row & 7) << 4));
}
__device__ inline bf16x8 lds_frag(const ushort* base, int row, int kk, int lane) {
    int kbyte = kk * 64 + (lane >> 4) * 16;
    return *(const bf16x8*)((const char*)base + swz(row, kbyte));
}
__device__ inline f32x4 mfma16(bf16x8 a, bf16x8 b, f32x4 c) {
    return __builtin_amdgcn_mfma_f32_16x16x32_bf16(a, b, c, 0, 0, 0);
}

// =====================================================================
// ctxT[b][d][s] (bf16) <- transpose+convert ctx[b][s][d] fp32. 64x64 tiles.
// =====================================================================
__global__ __launch_bounds__(256) void ctxT_kernel(
    const float* __restrict__ ctx, ushort* __restrict__ ctxT)
{
    const int b = blockIdx.z, d0 = blockIdx.x * 64, s0 = blockIdx.y * 64;
    __shared__ ushort T[64][72];   // T[d][s], row=144B (16B aligned)
    const int t = threadIdx.x;
    const float* src = ctx + ((size_t)b * LS + s0) * D + d0;
    const int r = t >> 4;          // s-row 0..15 per pass
    const int c = (t & 15) * 4;    // d-col
#pragma unroll
    for (int p = 0; p < 4; ++p) {
        float4 v = *(const float4*)(src + (size_t)(r + p * 16) * D + c);
        T[c + 0][r + p * 16] = f2bf(v.x);
        T[c + 1][r + p * 16] = f2bf(v.y);
        T[c + 2][r + p * 16] = f2bf(v.z);
        T[c + 3][r + p * 16] = f2bf(v.w);
    }
    __syncthreads();
    ushort* dst = ctxT + ((size_t)b * D + d0) * LS + s0;
    const int rd = t >> 3;         // d-row 0..31 per pass
    const int sc = (t & 7) * 8;
#pragma unroll
    for (int p = 0; p < 2; ++p) {
        uint4 o = *(const uint4*)&T[rd + p * 32][sc];
        *(uint4*)(dst + (size_t)(rd + p * 32) * LS + sc) = o;
    }
}

// =====================================================================
// Wb (bf16) <- W fp32 (native [SD][D] layout)
// =====================================================================
__global__ __launch_bounds__(256) void wconv_kernel(
    const float* __restrict__ W, ushort* __restrict__ Wb)
{
    size_t i = ((size_t)blockIdx.x * 256 + threadIdx.x) * 8;
    float4 a = *(const float4*)(W + i);
    float4 b = *(const float4*)(W + i + 4);
    *(uint4*)(Wb + i) = pack8(a, b);
}

// =====================================================================
// gemm1: attnQ[b][q][s] = leaky( sum_d (query*matrix)[q][d] * ctx[s][d] )
// BM=64(q) BN=256(s) BK=64. 256 thr, 4 waves n-split, wave=64x64.
// =====================================================================
__global__ __launch_bounds__(256) void gemm1_kernel(
    const float* __restrict__ query, const float* __restrict__ mat,
    const float* __restrict__ ctx, float* __restrict__ attnQ)
{
    const int m0 = blockIdx.x * 64;
    const int b  = blockIdx.y;
    __shared__ ushort As[64 * 64];
    __shared__ ushort Bs[256 * 64];
    const int t = threadIdx.x;
    const int w = t >> 6, l = t & 63;

    const float* Qb = query + ((size_t)b * LQ + m0) * D;
    const float* Mb = mat   + ((size_t)b * LQ + m0) * D;
    const float* Cb = ctx   + (size_t)b * LS * D;

    f32x4 acc[4][4] = {};

    for (int k0 = 0; k0 < D; k0 += 64) {
        if (k0) __syncthreads();
        // stage A (q*m fused, fp32->bf16): 512 chunks of 8
#pragma unroll
        for (int j = 0; j < 2; ++j) {
            int c = t + j * 256;
            int row = c >> 3, ko = (c & 7) * 8;
            const float* qp = Qb + (size_t)row * D + k0 + ko;
            const float* mp = Mb + (size_t)row * D + k0 + ko;
            float4 q1 = *(const float4*)qp, q2 = *(const float4*)(qp + 4);
            float4 m1 = *(const float4*)mp, m2 = *(const float4*)(mp + 4);
            float4 p1{q1.x*m1.x, q1.y*m1.y, q1.z*m1.z, q1.w*m1.w};
            float4 p2{q2.x*m2.x, q2.y*m2.y, q2.z*m2.z, q2.w*m2.w};
            *(uint4*)((char*)As + swz(row, ko * 2)) = pack8(p1, p2);
        }
        // stage B (ctx fp32->bf16): 2048 chunks of 8
#pragma unroll
        for (int j = 0; j < 8; ++j) {
            int c = t + j * 256;
            int row = c >> 3, ko = (c & 7) * 8;
            const float* cp = Cb + (size_t)row * D + k0 + ko;
            float4 c1 = *(const float4*)cp, c2 = *(const float4*)(cp + 4);
            *(uint4*)((char*)Bs + swz(row, ko * 2)) = pack8(c1, c2);
        }
        __syncthreads();
#pragma unroll
        for (int kk = 0; kk < 2; ++kk) {
            bf16x8 af[4], bf[4];
#pragma unroll
            for (int i = 0; i < 4; ++i) af[i] = lds_frag(As, i * 16 + (l & 15), kk, l);
#pragma unroll
            for (int n = 0; n < 4; ++n) bf[n] = lds_frag(Bs, w * 64 + n * 16 + (l & 15), kk, l);
#pragma unroll
            for (int i = 0; i < 4; ++i)
#pragma unroll
                for (int n = 0; n < 4; ++n) acc[i][n] = mfma16(af[i], bf[n], acc[i][n]);
        }
    }
    float* Ob = attnQ + ((size_t)b * LQ + m0) * LS;
#pragma unroll
    for (int i = 0; i < 4; ++i)
#pragma unroll
        for (int n = 0; n < 4; ++n) {
            int col = w * 64 + n * 16 + (l & 15);
#pragma unroll
            for (int r = 0; r < 4; ++r) {
                int row = i * 16 + (l >> 4) * 4 + r;
                float v = acc[i][n][r];
                Ob[(size_t)row * LS + col] = v >= 0.f ? v : 0.1f * v;
            }
        }
}

// =====================================================================
// normsm: l2norm over q (columns of attnQ[b][q][s]) then softmax over s,
// writes attnT[b][q][s] bf16. One block per batch.
// =====================================================================
__global__ __launch_bounds__(256) void normsm_kernel(
    const float* __restrict__ attnQ, ushort* __restrict__ attnT,
    const int* __restrict__ smooth_p)
{
    const int b = blockIdx.x;
    __shared__ float inv[LS];
    const float* S = attnQ + (size_t)b * LQ * LS;
    const int t = threadIdx.x;
    float ss = 0.f;
    for (int q = 0; q < LQ; ++q) { float v = S[(size_t)q * LS + t]; ss += v * v; }
    inv[t] = 1.0f / (sqrtf(ss) + EPS);
    __syncthreads();
    const float sm = (float)(*smooth_p);
    const int w = t >> 6, l = t & 63;
    ushort* O = attnT + (size_t)b * LQ * LS;
    for (int q = w; q < LQ; q += 4) {
        float4 v  = *(const float4*)&S[(size_t)q * LS + l * 4];
        float4 iv = *(const float4*)&inv[l * 4];
        float x0 = v.x * iv.x * sm, x1 = v.y * iv.y * sm;
        float x2 = v.z * iv.z * sm, x3 = v.w * iv.w * sm;
        float mx = fmaxf(fmaxf(x0, x1), fmaxf(x2, x3));
#pragma unroll
        for (int off = 32; off; off >>= 1) mx = fmaxf(mx, __shfl_xor(mx, off));
        float e0 = __expf(x0 - mx), e1 = __expf(x1 - mx);
        float e2 = __expf(x2 - mx), e3 = __expf(x3 - mx);
        float s4 = e0 + e1 + e2 + e3;
#pragma unroll
        for (int off = 32; off; off >>= 1) s4 += __shfl_xor(s4, off);
        float rs = 1.0f / s4;
        ushort4 o{f2bf(e0 * rs), f2bf(e1 * rs), f2bf(e2 * rs), f2bf(e3 * rs)};
        *(ushort4*)&O[(size_t)q * LS + l * 4] = o;
    }
}

// =====================================================================
// gemm2: wctx[b][q][d] (bf16) = sum_s attnT[q][s] * ctxT[d][s]
// BM=128(q) BN=128(d) BK=64. 256 thr, 4 waves 2x2, wave=64x64.
// =====================================================================
__global__ __launch_bounds__(256) void gemm2_kernel(
    const ushort* __restrict__ attnT, const ushort* __restrict__ ctxT,
    ushort* __restrict__ wctx)
{
    const int n0 = blockIdx.x * 128;
    const int b  = blockIdx.y;
    __shared__ ushort As[128 * 64];
    __shared__ ushort Bs[128 * 64];
    const int t = threadIdx.x;
    const int w = t >> 6, l = t & 63;
    const int wr = (w >> 1) * 64, wc = (w & 1) * 64;

    const ushort* Ab = attnT + (size_t)b * LQ * LS;
    const ushort* Bb = ctxT  + ((size_t)b * D + n0) * LS;

    f32x4 acc[4][4] = {};

    for (int k0 = 0; k0 < LS; k0 += 64) {
        if (k0) __syncthreads();
#pragma unroll
        for (int j = 0; j < 4; ++j) {
            int c = t + j * 256;
            int row = c >> 3, ko = (c & 7) * 8;
            uint4 va = *(const uint4*)(Ab + (size_t)row * LS + k0 + ko);
            *(uint4*)((char*)As + swz(row, ko * 2)) = va;
            uint4 vb = *(const uint4*)(Bb + (size_t)row * LS + k0 + ko);
            *(uint4*)((char*)Bs + swz(row, ko * 2)) = vb;
        }
        __syncthreads();
#pragma unroll
        for (int kk = 0; kk < 2; ++kk) {
            bf16x8 af[4], bf[4];
#pragma unroll
            for (int i = 0; i < 4; ++i) af[i] = lds_frag(As, wr + i * 16 + (l & 15), kk, l);
#pragma unroll
            for (int n = 0; n < 4; ++n) bf[n] = lds_frag(Bs, wc + n * 16 + (l & 15), kk, l);
#pragma unroll
            for (int i = 0; i < 4; ++i)
#pragma unroll
                for (int n = 0; n < 4; ++n) acc[i][n] = mfma16(af[i], bf[n], acc[i][n]);
        }
    }
    ushort* Ob = wctx + (size_t)b * LQ * D + n0;
#pragma unroll
    for (int i = 0; i < 4; ++i)
#pragma unroll
        for (int n = 0; n < 4; ++n) {
            int col = wc + n * 16 + (l & 15);
#pragma unroll
            for (int r = 0; r < 4; ++r) {
                int row = wr + i * 16 + (l >> 4) * 4 + r;
                Ob[(size_t)row * D + col] = f2bf(acc[i][n][r]);
            }
        }
}

// =====================================================================
// prep: sr[b,q,d] (bf16) = (query - l2norm(wctx))^2. Block per (b,q) row.
// =====================================================================
__global__ __launch_bounds__(256) void prep_kernel(
    const ushort* __restrict__ wctx, const float* __restrict__ query,
    ushort* __restrict__ sr)
{
    const size_t row = blockIdx.x;
    const int t = threadIdx.x;
    __shared__ float sred[4];
    const ushort* Wc = wctx + row * D;
    uint2 u = *(const uint2*)(Wc + t * 4);
    float w0 = bf2f((ushort)(u.x & 0xffff)), w1 = bf2f((ushort)(u.x >> 16));
    float w2 = bf2f((ushort)(u.y & 0xffff)), w3 = bf2f((ushort)(u.y >> 16));
    float ss = w0*w0 + w1*w1 + w2*w2 + w3*w3;
#pragma unroll
    for (int off = 32; off; off >>= 1) ss += __shfl_xor(ss, off);
    if ((t & 63) == 0) sred[t >> 6] = ss;
    __syncthreads();
    float tot = sred[0] + sred[1] + sred[2] + sred[3];
    float inv = 1.0f / (sqrtf(tot) + EPS);
    float4 q = *(const float4*)(query + row * D + t * 4);
    float d0 = q.x - w0 * inv, d1 = q.y - w1 * inv;
    float d2 = q.z - w2 * inv, d3 = q.w - w3 * inv;
    ushort4 o{f2bf(d0 * d0), f2bf(d1 * d1), f2bf(d2 * d2), f2bf(d3 * d3)};
    *(ushort4*)(sr + row * D + t * 4) = o;
}

// =====================================================================
// gemm3+finalnorm: out[b][q][k] = l2norm_k( sum_d sr[q][d]*Wb[k][d] + bias[k] )
// BM=64(q) BN=256(k=all SD) BK=64. 256 thr, 4 waves n-split, wave=64x64.
// =====================================================================
__global__ __launch_bounds__(256) void gemm3_kernel(
    const ushort* __restrict__ sr, const ushort* __restrict__ Wb,
    const float* __restrict__ bias, float* __restrict__ out)
{
    const int m0 = blockIdx.x * 64;
    const int b  = blockIdx.y;
    __shared__ ushort As[64 * 64];
    __shared__ ushort Bs[256 * 64];
    __shared__ float red[64][5];
    __shared__ float invr[64];
    const int t = threadIdx.x;
    const int w = t >> 6, l = t & 63;

    const ushort* Ab = sr + ((size_t)b * LQ + m0) * D;

    f32x4 acc[4][4] = {};

    for (int k0 = 0; k0 < D; k0 += 64) {
        if (k0) __syncthreads();
#pragma unroll
        for (int j = 0; j < 2; ++j) {
            int c = t + j * 256;
            int row = c >> 3, ko = (c & 7) * 8;
            uint4 va = *(const uint4*)(Ab + (size_t)row * D + k0 + ko);
            *(uint4*)((char*)As + swz(row, ko * 2)) = va;
        }
#pragma unroll
        for (int j = 0; j < 8; ++j) {
            int c = t + j * 256;
            int row = c >> 3, ko = (c & 7) * 8;
            uint4 vb = *(const uint4*)(Wb + (size_t)row * D + k0 + ko);
            *(uint4*)((char*)Bs + swz(row, ko * 2)) = vb;
        }
        __syncthreads();
#pragma unroll
        for (int kk = 0; kk < 2; ++kk) {
            bf16x8 af[4], bf[4];
#pragma unroll
            for (int i = 0; i < 4; ++i) af[i] = lds_frag(As, i * 16 + (l & 15), kk, l);
#pragma unroll
            for (int n = 0; n < 4; ++n) bf[n] = lds_frag(Bs, w * 64 + n * 16 + (l & 15), kk, l);
#pragma unroll
            for (int i = 0; i < 4; ++i)
#pragma unroll
                for (int n = 0; n < 4; ++n) acc[i][n] = mfma16(af[i], bf[n], acc[i][n]);
        }
    }
    // bias add, per-row sumsq (cross-wave via LDS), l2norm, write
#pragma unroll
    for (int n = 0; n < 4; ++n) {
        float bv = bias[w * 64 + n * 16 + (l & 15)];
#pragma unroll
        for (int i = 0; i < 4; ++i)
#pragma unroll
            for (int r = 0; r < 4; ++r) acc[i][n][r] += bv;
    }
#pragma unroll
    for (int i = 0; i < 4; ++i)
#pragma unroll
        for (int r = 0; r < 4; ++r) {
            float p = 0.f;
#pragma unroll
            for (int n = 0; n < 4; ++n) p += acc[i][n][r] * acc[i][n][r];
#pragma unroll
            for (int off = 1; off < 16; off <<= 1) p += __shfl_xor(p, off);
            int rowl = i * 16 + (l >> 4) * 4 + r;
            if ((l & 15) == 0) red[rowl][w] = p;
        }
    __syncthreads();
    if (t < 64) {
        float s = red[t][0] + red[t][1] + red[t][2] + red[t][3];
        invr[t] = 1.0f / (sqrtf(s) + EPS);
    }
    __syncthreads();
    float* Ob = out + ((size_t)b * LQ + m0) * SD;
#pragma unroll
    for (int i = 0; i < 4; ++i)
#pragma unroll
        for (int r = 0; r < 4; ++r) {
            int rowl = i * 16 + (l >> 4) * 4 + r;
            float iv = invr[rowl];
#pragma unroll
            for (int n = 0; n < 4; ++n) {
                int col = w * 64 + n * 16 + (l & 15);
                Ob[(size_t)rowl * SD + col] = acc[i][n][r] * iv;
            }
        }
}

// =====================================================================
extern "C" void kernel_launch(void* const* d_in, const int* in_sizes, int n_in,
                              void* d_out, int out_size, void* d_ws, size_t ws_size,
                              hipStream_t stream)
{
    const float* query  = (const float*)d_in[0];
    const float* ctx    = (const float*)d_in[1];
    const float* mat    = (const float*)d_in[2];
    const float* W      = (const float*)d_in[3];
    const float* bias   = (const float*)d_in[4];
    const int*   smooth = (const int*)d_in[5];
    float* out = (float*)d_out;

    char* ws = (char*)d_ws;
    float*  attnQ = (float*)ws;                                    // 16 MiB
    ushort* attnT = (ushort*)(ws + (size_t)16 * 1024 * 1024);      //  8 MiB
    ushort* ctxT  = (ushort*)(ws + (size_t)24 * 1024 * 1024);      // 64 MiB
    ushort* Wb    = (ushort*)(ws + (size_t)88 * 1024 * 1024);      // 0.5 MiB
    ushort* wctx  = (ushort*)(ws + (size_t)(88 * 1024 + 512) * 1024); // 32 MiB
    ushort* sr    = ctxT;   // ctxT dead after gemm2; alias for sr (32 MiB)

    ctxT_kernel<<<dim3(D / 64, LS / 64, B), 256, 0, stream>>>(ctx, ctxT);
    wconv_kernel<<<dim3(SD * D / (256 * 8)), 256, 0, stream>>>(W, Wb);
    gemm1_kernel<<<dim3(LQ / 64, B), 256, 0, stream>>>(query, mat, ctx, attnQ);
    normsm_kernel<<<dim3(B), 256, 0, stream>>>(attnQ, attnT, smooth);
    gemm2_kernel<<<dim3(D / 128, B), 256, 0, stream>>>(attnT, ctxT, wctx);
    prep_kernel<<<dim3(B * LQ), 256, 0, stream>>>(wctx, query, sr);
    gemm3_kernel<<<dim3(LQ / 64, B), 256, 0, stream>>>(sr, Wb, bias, out);
}

// Round 3
// 245.575 us; speedup vs baseline: 2.0411x; 1.1230x over previous
//
#include <hip/hip_runtime.h>
#include <hip/hip_bf16.h>

constexpr int B  = 128;
constexpr int LQ = 128;
constexpr int LS = 256;
constexpr int D  = 1024;
constexpr int SD = 256;
constexpr float EPS = 1e-8f;

typedef __attribute__((ext_vector_type(8))) __bf16 bf16x8;
typedef __attribute__((ext_vector_type(4))) float f32x4;

__device__ inline ushort f2bf(float f) {
    union { float f; uint u; } v{f};
    uint r = v.u + 0x7fffu + ((v.u >> 16) & 1u);   // RNE
    return (ushort)(r >> 16);
}
__device__ inline float bf2f(ushort u) {
    union { uint u; float f; } v{(uint)u << 16};
    return v.f;
}
__device__ inline uint4 pack8(float4 a, float4 b) {
    union { ushort us[8]; uint4 u4; } r;
    r.us[0]=f2bf(a.x); r.us[1]=f2bf(a.y); r.us[2]=f2bf(a.z); r.us[3]=f2bf(a.w);
    r.us[4]=f2bf(b.x); r.us[5]=f2bf(b.y); r.us[6]=f2bf(b.z); r.us[7]=f2bf(b.w);
    return r.u4;
}
// LDS rows are 64 bf16 = 128 B; XOR-swizzle bank fix (G4 / m214 pattern)
__device__ inline int swz(int row, int kbyte) {
    return row * 128 + (kbyte ^ ((row & 7) << 4));
}
__device__ inline bf16x8 lds_frag(const ushort* base, int row, int kk, int lane) {
    int kbyte = kk * 64 + (lane >> 4) * 16;
    return *(const bf16x8*)((const char*)base + swz(row, kbyte));
}
__device__ inline f32x4 mfma16(bf16x8 a, bf16x8 b, f32x4 c) {
    return __builtin_amdgcn_mfma_f32_16x16x32_bf16(a, b, c, 0, 0, 0);
}

// =====================================================================
// ctxT[b][d][s] (bf16) <- transpose+convert ctx[b][s][d] fp32. 64x64 tiles.
// =====================================================================
__global__ __launch_bounds__(256) void ctxT_kernel(
    const float* __restrict__ ctx, ushort* __restrict__ ctxT)
{
    const int b = blockIdx.z, d0 = blockIdx.x * 64, s0 = blockIdx.y * 64;
    __shared__ ushort T[64][72];   // T[d][s]
    const int t = threadIdx.x;
    const float* src = ctx + ((size_t)b * LS + s0) * D + d0;
    const int r = t >> 4;          // s-row 0..15 per pass
    const int c = (t & 15) * 4;    // d-col
#pragma unroll
    for (int p = 0; p < 4; ++p) {
        float4 v = *(const float4*)(src + (size_t)(r + p * 16) * D + c);
        T[c + 0][r + p * 16] = f2bf(v.x);
        T[c + 1][r + p * 16] = f2bf(v.y);
        T[c + 2][r + p * 16] = f2bf(v.z);
        T[c + 3][r + p * 16] = f2bf(v.w);
    }
    __syncthreads();
    ushort* dst = ctxT + ((size_t)b * D + d0) * LS + s0;
    const int rd = t >> 3;         // d-row 0..31 per pass
    const int sc = (t & 7) * 8;
#pragma unroll
    for (int p = 0; p < 2; ++p) {
        uint4 o = *(const uint4*)&T[rd + p * 32][sc];
        *(uint4*)(dst + (size_t)(rd + p * 32) * LS + sc) = o;
    }
}

// =====================================================================
// Wb (bf16) <- W fp32
// =====================================================================
__global__ __launch_bounds__(256) void wconv_kernel(
    const float* __restrict__ W, ushort* __restrict__ Wb)
{
    size_t i = ((size_t)blockIdx.x * 256 + threadIdx.x) * 8;
    float4 a = *(const float4*)(W + i);
    float4 b = *(const float4*)(W + i + 4);
    *(uint4*)(Wb + i) = pack8(a, b);
}

// =====================================================================
// qm (bf16) = query * matrix   (streaming, 8 elems/thread)
// =====================================================================
__global__ __launch_bounds__(256) void qm_kernel(
    const float* __restrict__ query, const float* __restrict__ mat,
    ushort* __restrict__ qm)
{
    size_t i = ((size_t)blockIdx.x * 256 + threadIdx.x) * 8;
    float4 q1 = *(const float4*)(query + i), q2 = *(const float4*)(query + i + 4);
    float4 m1 = *(const float4*)(mat + i),   m2 = *(const float4*)(mat + i + 4);
    float4 p1{q1.x*m1.x, q1.y*m1.y, q1.z*m1.z, q1.w*m1.w};
    float4 p2{q2.x*m2.x, q2.y*m2.y, q2.z*m2.z, q2.w*m2.w};
    *(uint4*)(qm + i) = pack8(p1, p2);
}

// =====================================================================
// gemm1: attnQ[b][q][s] = leaky( sum_d qm[q][d] * ctx[s][d] )
// BM=64(q) BN=128(s) BK=64. 256 thr, waves 2x2 (wave 32x64).
// Double-buffered LDS, reg-staged prefetch.
// =====================================================================
__global__ __launch_bounds__(256) void gemm1_kernel(
    const ushort* __restrict__ qm, const float* __restrict__ ctx,
    float* __restrict__ attnQ)
{
    const int m0 = blockIdx.x * 64;     // q
    const int n0 = blockIdx.y * 128;    // s
    const int b  = blockIdx.z;
    __shared__ ushort As[2][64 * 64];
    __shared__ ushort Bs[2][128 * 64];
    const int t = threadIdx.x;
    const int w = t >> 6, l = t & 63;
    const int wm = (w >> 1) * 32, wn = (w & 1) * 64;

    const ushort* Ab = qm  + ((size_t)b * LQ + m0) * D;
    const float*  Bb = ctx + ((size_t)b * LS + n0) * D;

    const int r0 = t >> 3;         // staging row base 0..31
    const int k8 = (t & 7) * 8;    // staging k-offset (elements)

    f32x4 acc[2][4] = {};
    uint4 a0, a1;
    float4 br[8];

    // prologue: stage tile 0
    a0 = *(const uint4*)(Ab + (size_t)r0 * D + k8);
    a1 = *(const uint4*)(Ab + (size_t)(r0 + 32) * D + k8);
#pragma unroll
    for (int j = 0; j < 4; ++j) {
        const float* p = Bb + (size_t)(r0 + j * 32) * D + k8;
        br[j * 2]     = *(const float4*)p;
        br[j * 2 + 1] = *(const float4*)(p + 4);
    }
    *(uint4*)((char*)As[0] + swz(r0, k8 * 2))      = a0;
    *(uint4*)((char*)As[0] + swz(r0 + 32, k8 * 2)) = a1;
#pragma unroll
    for (int j = 0; j < 4; ++j)
        *(uint4*)((char*)Bs[0] + swz(r0 + j * 32, k8 * 2)) = pack8(br[j*2], br[j*2+1]);
    __syncthreads();

    int cur = 0;
#pragma unroll 1
    for (int ks = 0; ks < (D / 64) - 1; ++ks) {
        const int k0 = (ks + 1) * 64;
        // issue next-tile loads (stay in flight across MFMA)
        a0 = *(const uint4*)(Ab + (size_t)r0 * D + k0 + k8);
        a1 = *(const uint4*)(Ab + (size_t)(r0 + 32) * D + k0 + k8);
#pragma unroll
        for (int j = 0; j < 4; ++j) {
            const float* p = Bb + (size_t)(r0 + j * 32) * D + k0 + k8;
            br[j * 2]     = *(const float4*)p;
            br[j * 2 + 1] = *(const float4*)(p + 4);
        }
        // compute current buffer
#pragma unroll
        for (int kk = 0; kk < 2; ++kk) {
            bf16x8 af[2], bfr[4];
#pragma unroll
            for (int i = 0; i < 2; ++i) af[i] = lds_frag(As[cur], wm + i * 16 + (l & 15), kk, l);
#pragma unroll
            for (int n = 0; n < 4; ++n) bfr[n] = lds_frag(Bs[cur], wn + n * 16 + (l & 15), kk, l);
#pragma unroll
            for (int i = 0; i < 2; ++i)
#pragma unroll
                for (int n = 0; n < 4; ++n) acc[i][n] = mfma16(af[i], bfr[n], acc[i][n]);
        }
        // write next buffer
        *(uint4*)((char*)As[cur ^ 1] + swz(r0, k8 * 2))      = a0;
        *(uint4*)((char*)As[cur ^ 1] + swz(r0 + 32, k8 * 2)) = a1;
#pragma unroll
        for (int j = 0; j < 4; ++j)
            *(uint4*)((char*)Bs[cur ^ 1] + swz(r0 + j * 32, k8 * 2)) = pack8(br[j*2], br[j*2+1]);
        __syncthreads();
        cur ^= 1;
    }
    // final tile compute
#pragma unroll
    for (int kk = 0; kk < 2; ++kk) {
        bf16x8 af[2], bfr[4];
#pragma unroll
        for (int i = 0; i < 2; ++i) af[i] = lds_frag(As[cur], wm + i * 16 + (l & 15), kk, l);
#pragma unroll
        for (int n = 0; n < 4; ++n) bfr[n] = lds_frag(Bs[cur], wn + n * 16 + (l & 15), kk, l);
#pragma unroll
        for (int i = 0; i < 2; ++i)
#pragma unroll
            for (int n = 0; n < 4; ++n) acc[i][n] = mfma16(af[i], bfr[n], acc[i][n]);
    }

    float* Ob = attnQ + ((size_t)b * LQ + m0) * LS + n0;
#pragma unroll
    for (int i = 0; i < 2; ++i)
#pragma unroll
        for (int n = 0; n < 4; ++n) {
            int col = wn + n * 16 + (l & 15);
#pragma unroll
            for (int r = 0; r < 4; ++r) {
                int row = wm + i * 16 + (l >> 4) * 4 + r;
                float v = acc[i][n][r];
                Ob[(size_t)row * LS + col] = v >= 0.f ? v : 0.1f * v;
            }
        }
}

// =====================================================================
// normsm: l2norm over q then softmax over s, writes attnT[b][q][s] bf16.
// =====================================================================
__global__ __launch_bounds__(256) void normsm_kernel(
    const float* __restrict__ attnQ, ushort* __restrict__ attnT,
    const int* __restrict__ smooth_p)
{
    const int b = blockIdx.x;
    __shared__ float inv[LS];
    const float* S = attnQ + (size_t)b * LQ * LS;
    const int t = threadIdx.x;
    float ss = 0.f;
    for (int q = 0; q < LQ; ++q) { float v = S[(size_t)q * LS + t]; ss += v * v; }
    inv[t] = 1.0f / (sqrtf(ss) + EPS);
    __syncthreads();
    const float sm = (float)(*smooth_p);
    const int w = t >> 6, l = t & 63;
    ushort* O = attnT + (size_t)b * LQ * LS;
    for (int q = w; q < LQ; q += 4) {
        float4 v  = *(const float4*)&S[(size_t)q * LS + l * 4];
        float4 iv = *(const float4*)&inv[l * 4];
        float x0 = v.x * iv.x * sm, x1 = v.y * iv.y * sm;
        float x2 = v.z * iv.z * sm, x3 = v.w * iv.w * sm;
        float mx = fmaxf(fmaxf(x0, x1), fmaxf(x2, x3));
#pragma unroll
        for (int off = 32; off; off >>= 1) mx = fmaxf(mx, __shfl_xor(mx, off));
        float e0 = __expf(x0 - mx), e1 = __expf(x1 - mx);
        float e2 = __expf(x2 - mx), e3 = __expf(x3 - mx);
        float s4 = e0 + e1 + e2 + e3;
#pragma unroll
        for (int off = 32; off; off >>= 1) s4 += __shfl_xor(s4, off);
        float rs = 1.0f / s4;
        ushort4 o{f2bf(e0 * rs), f2bf(e1 * rs), f2bf(e2 * rs), f2bf(e3 * rs)};
        *(ushort4*)&O[(size_t)q * LS + l * 4] = o;
    }
}

// =====================================================================
// gemm2: wctx[b][q][d] (bf16) = sum_s attnT[q][s] * ctxT[d][s]
// BM=128(q) BN=128(d) BK=64. 256 thr, 4 waves 2x2, wave=64x64.
// =====================================================================
__global__ __launch_bounds__(256) void gemm2_kernel(
    const ushort* __restrict__ attnT, const ushort* __restrict__ ctxT,
    ushort* __restrict__ wctx)
{
    const int n0 = blockIdx.x * 128;
    const int b  = blockIdx.y;
    __shared__ ushort As[128 * 64];
    __shared__ ushort Bs[128 * 64];
    const int t = threadIdx.x;
    const int w = t >> 6, l = t & 63;
    const int wr = (w >> 1) * 64, wc = (w & 1) * 64;

    const ushort* Ab = attnT + (size_t)b * LQ * LS;
    const ushort* Bb = ctxT  + ((size_t)b * D + n0) * LS;

    f32x4 acc[4][4] = {};

    for (int k0 = 0; k0 < LS; k0 += 64) {
        if (k0) __syncthreads();
#pragma unroll
        for (int j = 0; j < 4; ++j) {
            int c = t + j * 256;
            int row = c >> 3, ko = (c & 7) * 8;
            uint4 va = *(const uint4*)(Ab + (size_t)row * LS + k0 + ko);
            *(uint4*)((char*)As + swz(row, ko * 2)) = va;
            uint4 vb = *(const uint4*)(Bb + (size_t)row * LS + k0 + ko);
            *(uint4*)((char*)Bs + swz(row, ko * 2)) = vb;
        }
        __syncthreads();
#pragma unroll
        for (int kk = 0; kk < 2; ++kk) {
            bf16x8 af[4], bf[4];
#pragma unroll
            for (int i = 0; i < 4; ++i) af[i] = lds_frag(As, wr + i * 16 + (l & 15), kk, l);
#pragma unroll
            for (int n = 0; n < 4; ++n) bf[n] = lds_frag(Bs, wc + n * 16 + (l & 15), kk, l);
#pragma unroll
            for (int i = 0; i < 4; ++i)
#pragma unroll
                for (int n = 0; n < 4; ++n) acc[i][n] = mfma16(af[i], bf[n], acc[i][n]);
        }
    }
    ushort* Ob = wctx + (size_t)b * LQ * D + n0;
#pragma unroll
    for (int i = 0; i < 4; ++i)
#pragma unroll
        for (int n = 0; n < 4; ++n) {
            int col = wc + n * 16 + (l & 15);
#pragma unroll
            for (int r = 0; r < 4; ++r) {
                int row = wr + i * 16 + (l >> 4) * 4 + r;
                Ob[(size_t)row * D + col] = f2bf(acc[i][n][r]);
            }
        }
}

// =====================================================================
// prep: sr[b,q,d] (bf16) = (query - l2norm(wctx))^2. Block per (b,q) row.
// =====================================================================
__global__ __launch_bounds__(256) void prep_kernel(
    const ushort* __restrict__ wctx, const float* __restrict__ query,
    ushort* __restrict__ sr)
{
    const size_t row = blockIdx.x;
    const int t = threadIdx.x;
    __shared__ float sred[4];
    const ushort* Wc = wctx + row * D;
    uint2 u = *(const uint2*)(Wc + t * 4);
    float w0 = bf2f((ushort)(u.x & 0xffff)), w1 = bf2f((ushort)(u.x >> 16));
    float w2 = bf2f((ushort)(u.y & 0xffff)), w3 = bf2f((ushort)(u.y >> 16));
    float ss = w0*w0 + w1*w1 + w2*w2 + w3*w3;
#pragma unroll
    for (int off = 32; off; off >>= 1) ss += __shfl_xor(ss, off);
    if ((t & 63) == 0) sred[t >> 6] = ss;
    __syncthreads();
    float tot = sred[0] + sred[1] + sred[2] + sred[3];
    float inv = 1.0f / (sqrtf(tot) + EPS);
    float4 q = *(const float4*)(query + row * D + t * 4);
    float d0 = q.x - w0 * inv, d1 = q.y - w1 * inv;
    float d2 = q.z - w2 * inv, d3 = q.w - w3 * inv;
    ushort4 o{f2bf(d0 * d0), f2bf(d1 * d1), f2bf(d2 * d2), f2bf(d3 * d3)};
    *(ushort4*)(sr + row * D + t * 4) = o;
}

// =====================================================================
// gemm3+finalnorm: out[b][q][k] = l2norm_k( sum_d sr[q][d]*Wb[k][d] + b[k] )
// BM=64(q) BN=256(all SD) BK=64. 512 thr, 8 waves 2x4 (wave 32x64).
// =====================================================================
__global__ __launch_bounds__(512) void gemm3_kernel(
    const ushort* __restrict__ sr, const ushort* __restrict__ Wb,
    const float* __restrict__ bias, float* __restrict__ out)
{
    const int m0 = blockIdx.x * 64;
    const int b  = blockIdx.y;
    __shared__ ushort As[64 * 64];
    __shared__ ushort Bs[256 * 64];
    __shared__ float red[64][4];
    __shared__ float invr[64];
    const int t = threadIdx.x;
    const int w = t >> 6, l = t & 63;
    const int wm = (w >> 2) * 32, wn = (w & 3) * 64;

    const ushort* Ab = sr + ((size_t)b * LQ + m0) * D;

    f32x4 acc[2][4] = {};

    for (int k0 = 0; k0 < D; k0 += 64) {
        if (k0) __syncthreads();
        {   // A: 64x64 = 512 chunks, 1/thread
            int row = t >> 3, ko = (t & 7) * 8;
            *(uint4*)((char*)As + swz(row, ko * 2)) =
                *(const uint4*)(Ab + (size_t)row * D + k0 + ko);
        }
#pragma unroll
        for (int j = 0; j < 4; ++j) {   // B: 256x64 = 2048 chunks, 4/thread
            int c = t + j * 512;
            int row = c >> 3, ko = (c & 7) * 8;
            *(uint4*)((char*)Bs + swz(row, ko * 2)) =
                *(const uint4*)(Wb + (size_t)row * D + k0 + ko);
        }
        __syncthreads();
#pragma unroll
        for (int kk = 0; kk < 2; ++kk) {
            bf16x8 af[2], bfr[4];
#pragma unroll
            for (int i = 0; i < 2; ++i) af[i] = lds_frag(As, wm + i * 16 + (l & 15), kk, l);
#pragma unroll
            for (int n = 0; n < 4; ++n) bfr[n] = lds_frag(Bs, wn + n * 16 + (l & 15), kk, l);
#pragma unroll
            for (int i = 0; i < 2; ++i)
#pragma unroll
                for (int n = 0; n < 4; ++n) acc[i][n] = mfma16(af[i], bfr[n], acc[i][n]);
        }
    }
    // bias add, per-row sumsq (cross-wave via LDS), l2norm, write
#pragma unroll
    for (int n = 0; n < 4; ++n) {
        float bv = bias[wn + n * 16 + (l & 15)];
#pragma unroll
        for (int i = 0; i < 2; ++i)
#pragma unroll
            for (int r = 0; r < 4; ++r) acc[i][n][r] += bv;
    }
#pragma unroll
    for (int i = 0; i < 2; ++i)
#pragma unroll
        for (int r = 0; r < 4; ++r) {
            float p = 0.f;
#pragma unroll
            for (int n = 0; n < 4; ++n) p += acc[i][n][r] * acc[i][n][r];
#pragma unroll
            for (int off = 1; off < 16; off <<= 1) p += __shfl_xor(p, off);
            int rowl = wm + i * 16 + (l >> 4) * 4 + r;
            if ((l & 15) == 0) red[rowl][w & 3] = p;
        }
    __syncthreads();
    if (t < 64) {
        float s = red[t][0] + red[t][1] + red[t][2] + red[t][3];
        invr[t] = 1.0f / (sqrtf(s) + EPS);
    }
    __syncthreads();
    float* Ob = out + ((size_t)b * LQ + m0) * SD;
#pragma unroll
    for (int i = 0; i < 2; ++i)
#pragma unroll
        for (int r = 0; r < 4; ++r) {
            int rowl = wm + i * 16 + (l >> 4) * 4 + r;
            float iv = invr[rowl];
#pragma unroll
            for (int n = 0; n < 4; ++n) {
                int col = wn + n * 16 + (l & 15);
                Ob[(size_t)rowl * SD + col] = acc[i][n][r] * iv;
            }
        }
}

// =====================================================================
extern "C" void kernel_launch(void* const* d_in, const int* in_sizes, int n_in,
                              void* d_out, int out_size, void* d_ws, size_t ws_size,
                              hipStream_t stream)
{
    const float* query  = (const float*)d_in[0];
    const float* ctx    = (const float*)d_in[1];
    const float* mat    = (const float*)d_in[2];
    const float* W      = (const float*)d_in[3];
    const float* bias   = (const float*)d_in[4];
    const int*   smooth = (const int*)d_in[5];
    float* out = (float*)d_out;

    char* ws = (char*)d_ws;
    float*  attnQ = (float*)ws;                                    // 16 MiB
    ushort* attnT = (ushort*)(ws + (size_t)16 * 1024 * 1024);      //  8 MiB
    ushort* ctxT  = (ushort*)(ws + (size_t)24 * 1024 * 1024);      // 64 MiB
    ushort* Wb    = (ushort*)(ws + (size_t)88 * 1024 * 1024);      // 0.5 MiB
    ushort* wctx  = (ushort*)(ws + (size_t)(88 * 1024 + 512) * 1024); // 32 MiB
    ushort* qm    = wctx;   // qm dead before gemm2 writes wctx
    ushort* sr    = ctxT;   // ctxT dead after gemm2

    ctxT_kernel<<<dim3(D / 64, LS / 64, B), 256, 0, stream>>>(ctx, ctxT);
    wconv_kernel<<<dim3(SD * D / (256 * 8)), 256, 0, stream>>>(W, Wb);
    qm_kernel<<<dim3((size_t)B * LQ * D / (256 * 8)), 256, 0, stream>>>(query, mat, qm);
    gemm1_kernel<<<dim3(LQ / 64, LS / 128, B), 256, 0, stream>>>(qm, ctx, attnQ);
    normsm_kernel<<<dim3(B), 256, 0, stream>>>(attnQ, attnT, smooth);
    gemm2_kernel<<<dim3(D / 128, B), 256, 0, stream>>>(attnT, ctxT, wctx);
    prep_kernel<<<dim3(B * LQ), 256, 0, stream>>>(wctx, query, sr);
    gemm3_kernel<<<dim3(LQ / 64, B), 512, 0, stream>>>(sr, Wb, bias, out);
}

// Round 4
// 230.742 us; speedup vs baseline: 2.1723x; 1.0643x over previous
//
#include <hip/hip_runtime.h>
#include <hip/hip_bf16.h>

constexpr int B  = 128;
constexpr int LQ = 128;
constexpr int LS = 256;
constexpr int D  = 1024;
constexpr int SD = 256;
constexpr float EPS = 1e-8f;

typedef __attribute__((ext_vector_type(8))) __bf16 bf16x8;
typedef __attribute__((ext_vector_type(4))) float f32x4;

__device__ inline ushort f2bf(float f) {
    union { float f; uint u; } v{f};
    uint r = v.u + 0x7fffu + ((v.u >> 16) & 1u);   // RNE
    return (ushort)(r >> 16);
}
__device__ inline float bf2f(ushort u) {
    union { uint u; float f; } v{(uint)u << 16};
    return v.f;
}
__device__ inline uint4 pack8(float4 a, float4 b) {
    union { ushort us[8]; uint4 u4; } r;
    r.us[0]=f2bf(a.x); r.us[1]=f2bf(a.y); r.us[2]=f2bf(a.z); r.us[3]=f2bf(a.w);
    r.us[4]=f2bf(b.x); r.us[5]=f2bf(b.y); r.us[6]=f2bf(b.z); r.us[7]=f2bf(b.w);
    return r.u4;
}
// 128B-row LDS tiles (64 bf16): XOR-swizzle bank fix
__device__ inline int swz(int row, int kbyte) {
    return row * 128 + (kbyte ^ ((row & 7) << 4));
}
__device__ inline bf16x8 lds_frag(const ushort* base, int row, int kk, int lane) {
    int kbyte = kk * 64 + (lane >> 4) * 16;
    return *(const bf16x8*)((const char*)base + swz(row, kbyte));
}
// 512B-row LDS tiles (256 bf16): same XOR pattern
__device__ inline int swz512(int row, int kbyte) {
    return row * 512 + (kbyte ^ ((row & 7) << 4));
}
__device__ inline f32x4 mfma16(bf16x8 a, bf16x8 b, f32x4 c) {
    return __builtin_amdgcn_mfma_f32_16x16x32_bf16(a, b, c, 0, 0, 0);
}

// =====================================================================
// ctxT[b][d][s] (bf16) <- transpose+convert ctx[b][s][d] fp32. 64x64 tiles.
// =====================================================================
__global__ __launch_bounds__(256) void ctxT_kernel(
    const float* __restrict__ ctx, ushort* __restrict__ ctxT)
{
    const int b = blockIdx.z, d0 = blockIdx.x * 64, s0 = blockIdx.y * 64;
    __shared__ ushort T[64][72];   // T[d][s]
    const int t = threadIdx.x;
    const float* src = ctx + ((size_t)b * LS + s0) * D + d0;
    const int r = t >> 4;
    const int c = (t & 15) * 4;
#pragma unroll
    for (int p = 0; p < 4; ++p) {
        float4 v = *(const float4*)(src + (size_t)(r + p * 16) * D + c);
        T[c + 0][r + p * 16] = f2bf(v.x);
        T[c + 1][r + p * 16] = f2bf(v.y);
        T[c + 2][r + p * 16] = f2bf(v.z);
        T[c + 3][r + p * 16] = f2bf(v.w);
    }
    __syncthreads();
    ushort* dst = ctxT + ((size_t)b * D + d0) * LS + s0;
    const int rd = t >> 3;
    const int sc = (t & 7) * 8;
#pragma unroll
    for (int p = 0; p < 2; ++p) {
        uint4 o = *(const uint4*)&T[rd + p * 32][sc];
        *(uint4*)(dst + (size_t)(rd + p * 32) * LS + sc) = o;
    }
}

// =====================================================================
// Wb (bf16) <- W fp32
// =====================================================================
__global__ __launch_bounds__(256) void wconv_kernel(
    const float* __restrict__ W, ushort* __restrict__ Wb)
{
    size_t i = ((size_t)blockIdx.x * 256 + threadIdx.x) * 8;
    float4 a = *(const float4*)(W + i);
    float4 b = *(const float4*)(W + i + 4);
    *(uint4*)(Wb + i) = pack8(a, b);
}

// =====================================================================
// gemm1: attn[b][q][s] = leaky( sum_d (query*matrix)[q][d] * ctx[s][d] )
// BM=64(q) BN=128(s) BK=64. 256 thr, waves 2x2 (wave 32x64). Dbuf.
// qm fused into A staging. XCD-aware block remap (4 blocks of a batch
// share one XCD -> ctx[b] L2-hit for the 2nd m-block).
// =====================================================================
__global__ __launch_bounds__(256) void gemm1_kernel(
    const float* __restrict__ query, const float* __restrict__ mat,
    const float* __restrict__ ctx, float* __restrict__ attn)
{
    const int flat = blockIdx.x;          // 512 blocks
    const int xcd = flat & 7, idx = flat >> 3;
    const int b   = xcd * 16 + (idx >> 2);
    const int sub = idx & 3;
    const int m0  = (sub & 1) * 64;
    const int n0  = (sub >> 1) * 128;

    __shared__ ushort As[2][64 * 64];
    __shared__ ushort Bs[2][128 * 64];
    const int t = threadIdx.x;
    const int w = t >> 6, l = t & 63;
    const int wm = (w >> 1) * 32, wn = (w & 1) * 64;

    const float* Qb = query + ((size_t)b * LQ + m0) * D;
    const float* Mb = mat   + ((size_t)b * LQ + m0) * D;
    const float* Bb = ctx   + ((size_t)b * LS + n0) * D;

    const int r0 = t >> 3;         // 0..31
    const int k8 = (t & 7) * 8;

    f32x4 acc[2][4] = {};
    float4 aq[4], am[4];           // A: 2 rows x 2 halves (query, matrix)
    float4 br[8];

    // prologue: stage tile 0
#pragma unroll
    for (int h = 0; h < 2; ++h) {
        const float* qp = Qb + (size_t)(r0 + h * 32) * D + k8;
        const float* mp = Mb + (size_t)(r0 + h * 32) * D + k8;
        aq[h*2] = *(const float4*)qp; aq[h*2+1] = *(const float4*)(qp + 4);
        am[h*2] = *(const float4*)mp; am[h*2+1] = *(const float4*)(mp + 4);
    }
#pragma unroll
    for (int j = 0; j < 4; ++j) {
        const float* p = Bb + (size_t)(r0 + j * 32) * D + k8;
        br[j*2] = *(const float4*)p; br[j*2+1] = *(const float4*)(p + 4);
    }
#pragma unroll
    for (int h = 0; h < 2; ++h) {
        float4 p1{aq[h*2].x*am[h*2].x, aq[h*2].y*am[h*2].y, aq[h*2].z*am[h*2].z, aq[h*2].w*am[h*2].w};
        float4 p2{aq[h*2+1].x*am[h*2+1].x, aq[h*2+1].y*am[h*2+1].y, aq[h*2+1].z*am[h*2+1].z, aq[h*2+1].w*am[h*2+1].w};
        *(uint4*)((char*)As[0] + swz(r0 + h * 32, k8 * 2)) = pack8(p1, p2);
    }
#pragma unroll
    for (int j = 0; j < 4; ++j)
        *(uint4*)((char*)Bs[0] + swz(r0 + j * 32, k8 * 2)) = pack8(br[j*2], br[j*2+1]);
    __syncthreads();

    int cur = 0;
#pragma unroll 1
    for (int ks = 0; ks < (D / 64) - 1; ++ks) {
        const int k0 = (ks + 1) * 64;
#pragma unroll
        for (int h = 0; h < 2; ++h) {
            const float* qp = Qb + (size_t)(r0 + h * 32) * D + k0 + k8;
            const float* mp = Mb + (size_t)(r0 + h * 32) * D + k0 + k8;
            aq[h*2] = *(const float4*)qp; aq[h*2+1] = *(const float4*)(qp + 4);
            am[h*2] = *(const float4*)mp; am[h*2+1] = *(const float4*)(mp + 4);
        }
#pragma unroll
        for (int j = 0; j < 4; ++j) {
            const float* p = Bb + (size_t)(r0 + j * 32) * D + k0 + k8;
            br[j*2] = *(const float4*)p; br[j*2+1] = *(const float4*)(p + 4);
        }
#pragma unroll
        for (int kk = 0; kk < 2; ++kk) {
            bf16x8 af[2], bfr[4];
#pragma unroll
            for (int i = 0; i < 2; ++i) af[i] = lds_frag(As[cur], wm + i * 16 + (l & 15), kk, l);
#pragma unroll
            for (int n = 0; n < 4; ++n) bfr[n] = lds_frag(Bs[cur], wn + n * 16 + (l & 15), kk, l);
#pragma unroll
            for (int i = 0; i < 2; ++i)
#pragma unroll
                for (int n = 0; n < 4; ++n) acc[i][n] = mfma16(af[i], bfr[n], acc[i][n]);
        }
#pragma unroll
        for (int h = 0; h < 2; ++h) {
            float4 p1{aq[h*2].x*am[h*2].x, aq[h*2].y*am[h*2].y, aq[h*2].z*am[h*2].z, aq[h*2].w*am[h*2].w};
            float4 p2{aq[h*2+1].x*am[h*2+1].x, aq[h*2+1].y*am[h*2+1].y, aq[h*2+1].z*am[h*2+1].z, aq[h*2+1].w*am[h*2+1].w};
            *(uint4*)((char*)As[cur ^ 1] + swz(r0 + h * 32, k8 * 2)) = pack8(p1, p2);
        }
#pragma unroll
        for (int j = 0; j < 4; ++j)
            *(uint4*)((char*)Bs[cur ^ 1] + swz(r0 + j * 32, k8 * 2)) = pack8(br[j*2], br[j*2+1]);
        __syncthreads();
        cur ^= 1;
    }
#pragma unroll
    for (int kk = 0; kk < 2; ++kk) {
        bf16x8 af[2], bfr[4];
#pragma unroll
        for (int i = 0; i < 2; ++i) af[i] = lds_frag(As[cur], wm + i * 16 + (l & 15), kk, l);
#pragma unroll
        for (int n = 0; n < 4; ++n) bfr[n] = lds_frag(Bs[cur], wn + n * 16 + (l & 15), kk, l);
#pragma unroll
        for (int i = 0; i < 2; ++i)
#pragma unroll
            for (int n = 0; n < 4; ++n) acc[i][n] = mfma16(af[i], bfr[n], acc[i][n]);
    }

    float* Ob = attn + ((size_t)b * LQ + m0) * LS + n0;
#pragma unroll
    for (int i = 0; i < 2; ++i)
#pragma unroll
        for (int n = 0; n < 4; ++n) {
            int col = wn + n * 16 + (l & 15);
#pragma unroll
            for (int r = 0; r < 4; ++r) {
                int row = wm + i * 16 + (l >> 4) * 4 + r;
                float v = acc[i][n][r];
                Ob[(size_t)row * LS + col] = v >= 0.f ? v : 0.1f * v;
            }
        }
}

// =====================================================================
// mid: per batch — col-l2norm(q) + softmax(s) + PV GEMM + row sumsq.
//   P[q][s] bf16 in LDS; Bs staged from ctxT per 128-d tile.
//   Outputs wctx[b][q][d] bf16 (unnormalized) and invq[b][q] f32.
// 512 thr (8 waves: 2q x 4d for PV).
// =====================================================================
__global__ __launch_bounds__(512) void mid_kernel(
    const float* __restrict__ attn, const ushort* __restrict__ ctxT,
    const int* __restrict__ smooth_p, ushort* __restrict__ wctx,
    float* __restrict__ invq)
{
    const int b = blockIdx.x;
    __shared__ ushort P[128 * 256];        // swizzled 512B rows (64KB)
    __shared__ ushort Bs[128 * 256];       // swizzled 512B rows (64KB)
    __shared__ __align__(16) float colss[2][256];
    __shared__ __align__(16) float inv_s[256];
    __shared__ float rowss[128][4];
    const int t = threadIdx.x;
    const int wv = t >> 6, l = t & 63;

    const float* Ab = attn + (size_t)b * LQ * LS;

    // phase 1: column (over q) sumsq -> inv_s
    {
        const int s = t & 255, q0 = t >> 8;
        float ss = 0.f;
        for (int q = q0; q < LQ; q += 2) {
            float v = Ab[(size_t)q * LS + s];
            ss += v * v;
        }
        colss[q0][s] = ss;
    }
    rowss[t >> 2][t & 3] = 0.f;
    __syncthreads();
    if (t < 256) inv_s[t] = 1.0f / (sqrtf(colss[0][t] + colss[1][t]) + EPS);
    __syncthreads();

    // phase 2: per-q softmax over s -> P bf16 (one wave per row)
    const float sm = (float)(*smooth_p);
    for (int q = wv; q < LQ; q += 8) {
        float4 v  = *(const float4*)&Ab[(size_t)q * LS + l * 4];
        float4 iv = *(const float4*)&inv_s[l * 4];
        float x0 = v.x * iv.x * sm, x1 = v.y * iv.y * sm;
        float x2 = v.z * iv.z * sm, x3 = v.w * iv.w * sm;
        float mx = fmaxf(fmaxf(x0, x1), fmaxf(x2, x3));
#pragma unroll
        for (int off = 32; off; off >>= 1) mx = fmaxf(mx, __shfl_xor(mx, off));
        float e0 = __expf(x0 - mx), e1 = __expf(x1 - mx);
        float e2 = __expf(x2 - mx), e3 = __expf(x3 - mx);
        float s4 = e0 + e1 + e2 + e3;
#pragma unroll
        for (int off = 32; off; off >>= 1) s4 += __shfl_xor(s4, off);
        float rs = 1.0f / s4;
        ushort4 o{f2bf(e0 * rs), f2bf(e1 * rs), f2bf(e2 * rs), f2bf(e3 * rs)};
        *(ushort4*)((char*)P + swz512(q, l * 8)) = o;
    }

    // phase 3: PV — wctx[q][d] = sum_s P[q][s] * ctxT[d][s]
    const ushort* Cb = ctxT + (size_t)b * D * LS;
    const int wq = wv >> 2, wd = wv & 3;
    const int cc = t & 31, rr = t >> 5;    // staging coords
#pragma unroll 1
    for (int dt = 0; dt < 8; ++dt) {
        __syncthreads();   // P ready (dt=0) / Bs free (dt>0)
#pragma unroll
        for (int it = 0; it < 8; ++it) {
            int row = rr + it * 16;
            uint4 v = *(const uint4*)(Cb + (size_t)(dt * 128 + row) * LS + cc * 8);
            *(uint4*)((char*)Bs + swz512(row, cc * 16)) = v;
        }
        __syncthreads();
        f32x4 acc[4][2] = {};
#pragma unroll
        for (int kk = 0; kk < 8; ++kk) {
            bf16x8 af[4], bfr[2];
            int kb = kk * 64 + (l >> 4) * 16;
#pragma unroll
            for (int i = 0; i < 4; ++i) {
                int row = wq * 64 + i * 16 + (l & 15);
                af[i] = *(const bf16x8*)((const char*)P + swz512(row, kb));
            }
#pragma unroll
            for (int n = 0; n < 2; ++n) {
                int row = wd * 32 + n * 16 + (l & 15);
                bfr[n] = *(const bf16x8*)((const char*)Bs + swz512(row, kb));
            }
#pragma unroll
            for (int i = 0; i < 4; ++i)
#pragma unroll
                for (int n = 0; n < 2; ++n) acc[i][n] = mfma16(af[i], bfr[n], acc[i][n]);
        }
        ushort* Ob = wctx + (size_t)b * LQ * D + dt * 128 + wd * 32;
#pragma unroll
        for (int i = 0; i < 4; ++i)
#pragma unroll
            for (int r = 0; r < 4; ++r) {
                int row = wq * 64 + i * 16 + (l >> 4) * 4 + r;
                float p2 = acc[i][0][r] * acc[i][0][r] + acc[i][1][r] * acc[i][1][r];
#pragma unroll
                for (int off = 1; off < 16; off <<= 1) p2 += __shfl_xor(p2, off);
                if ((l & 15) == 0) rowss[row][wd] += p2;
                Ob[(size_t)row * D + (l & 15)]      = f2bf(acc[i][0][r]);
                Ob[(size_t)row * D + 16 + (l & 15)] = f2bf(acc[i][1][r]);
            }
    }
    __syncthreads();
    if (t < 128) {
        float s4 = rowss[t][0] + rowss[t][1] + rowss[t][2] + rowss[t][3];
        invq[(size_t)b * LQ + t] = 1.0f / (sqrtf(s4) + EPS);
    }
}

// =====================================================================
// gemm3+finalnorm: out[b][q][k] = l2norm_k( sum_d sr[q][d]*Wb[k][d] + b[k] )
// sr computed on the fly: (query - wctx*invq)^2.
// BM=64(q) BN=256 BK=64. 512 thr, 8 waves 2x4.
// =====================================================================
__global__ __launch_bounds__(512) void gemm3_kernel(
    const ushort* __restrict__ wctx, const float* __restrict__ query,
    const float* __restrict__ invq, const ushort* __restrict__ Wb,
    const float* __restrict__ bias, float* __restrict__ out)
{
    const int m0 = blockIdx.x * 64;
    const int b  = blockIdx.y;
    __shared__ ushort As[64 * 64];
    __shared__ ushort Bs[256 * 64];
    __shared__ float red[64][4];
    __shared__ float invr[64];
    const int t = threadIdx.x;
    const int w = t >> 6, l = t & 63;
    const int wm = (w >> 2) * 32, wn = (w & 3) * 64;

    const int arow = t >> 3, ako = (t & 7) * 8;
    const float  ivq = invq[(size_t)b * LQ + m0 + arow];
    const float* Qp  = query + ((size_t)b * LQ + m0 + arow) * D + ako;
    const ushort* Wp = wctx  + ((size_t)b * LQ + m0 + arow) * D + ako;

    f32x4 acc[2][4] = {};

    for (int k0 = 0; k0 < D; k0 += 64) {
        if (k0) __syncthreads();
        {   // A: sr on the fly
            uint4 wu = *(const uint4*)(Wp + k0);
            float4 q1 = *(const float4*)(Qp + k0);
            float4 q2 = *(const float4*)(Qp + k0 + 4);
            float d0 = q1.x - bf2f((ushort)(wu.x & 0xffff)) * ivq;
            float d1 = q1.y - bf2f((ushort)(wu.x >> 16))    * ivq;
            float d2 = q1.z - bf2f((ushort)(wu.y & 0xffff)) * ivq;
            float d3 = q1.w - bf2f((ushort)(wu.y >> 16))    * ivq;
            float d4 = q2.x - bf2f((ushort)(wu.z & 0xffff)) * ivq;
            float d5 = q2.y - bf2f((ushort)(wu.z >> 16))    * ivq;
            float d6 = q2.z - bf2f((ushort)(wu.w & 0xffff)) * ivq;
            float d7 = q2.w - bf2f((ushort)(wu.w >> 16))    * ivq;
            float4 s1{d0*d0, d1*d1, d2*d2, d3*d3};
            float4 s2{d4*d4, d5*d5, d6*d6, d7*d7};
            *(uint4*)((char*)As + swz(arow, ako * 2)) = pack8(s1, s2);
        }
#pragma unroll
        for (int j = 0; j < 4; ++j) {   // B: Wb
            int c = t + j * 512;
            int row = c >> 3, ko = (c & 7) * 8;
            *(uint4*)((char*)Bs + swz(row, ko * 2)) =
                *(const uint4*)(Wb + (size_t)row * D + k0 + ko);
        }
        __syncthreads();
#pragma unroll
        for (int kk = 0; kk < 2; ++kk) {
            bf16x8 af[2], bfr[4];
#pragma unroll
            for (int i = 0; i < 2; ++i) af[i] = lds_frag(As, wm + i * 16 + (l & 15), kk, l);
#pragma unroll
            for (int n = 0; n < 4; ++n) bfr[n] = lds_frag(Bs, wn + n * 16 + (l & 15), kk, l);
#pragma unroll
            for (int i = 0; i < 2; ++i)
#pragma unroll
                for (int n = 0; n < 4; ++n) acc[i][n] = mfma16(af[i], bfr[n], acc[i][n]);
        }
    }
#pragma unroll
    for (int n = 0; n < 4; ++n) {
        float bv = bias[wn + n * 16 + (l & 15)];
#pragma unroll
        for (int i = 0; i < 2; ++i)
#pragma unroll
            for (int r = 0; r < 4; ++r) acc[i][n][r] += bv;
    }
#pragma unroll
    for (int i = 0; i < 2; ++i)
#pragma unroll
        for (int r = 0; r < 4; ++r) {
            float p = 0.f;
#pragma unroll
            for (int n = 0; n < 4; ++n) p += acc[i][n][r] * acc[i][n][r];
#pragma unroll
            for (int off = 1; off < 16; off <<= 1) p += __shfl_xor(p, off);
            int rowl = wm + i * 16 + (l >> 4) * 4 + r;
            if ((l & 15) == 0) red[rowl][w & 3] = p;
        }
    __syncthreads();
    if (t < 64) {
        float s = red[t][0] + red[t][1] + red[t][2] + red[t][3];
        invr[t] = 1.0f / (sqrtf(s) + EPS);
    }
    __syncthreads();
    float* Ob = out + ((size_t)b * LQ + m0) * SD;
#pragma unroll
    for (int i = 0; i < 2; ++i)
#pragma unroll
        for (int r = 0; r < 4; ++r) {
            int rowl = wm + i * 16 + (l >> 4) * 4 + r;
            float iv = invr[rowl];
#pragma unroll
            for (int n = 0; n < 4; ++n) {
                int col = wn + n * 16 + (l & 15);
                Ob[(size_t)rowl * SD + col] = acc[i][n][r] * iv;
            }
        }
}

// =====================================================================
extern "C" void kernel_launch(void* const* d_in, const int* in_sizes, int n_in,
                              void* d_out, int out_size, void* d_ws, size_t ws_size,
                              hipStream_t stream)
{
    const float* query  = (const float*)d_in[0];
    const float* ctx    = (const float*)d_in[1];
    const float* mat    = (const float*)d_in[2];
    const float* W      = (const float*)d_in[3];
    const float* bias   = (const float*)d_in[4];
    const int*   smooth = (const int*)d_in[5];
    float* out = (float*)d_out;

    char* ws = (char*)d_ws;
    float*  attn = (float*)ws;                                  // 16 MiB
    ushort* wctx = (ushort*)(ws + (size_t)16 * 1024 * 1024);    // 32 MiB
    ushort* ctxT = (ushort*)(ws + (size_t)48 * 1024 * 1024);    // 64 MiB
    ushort* Wb   = (ushort*)(ws + (size_t)112 * 1024 * 1024);   // 0.5 MiB
    float*  invq = (float*)(ws + (size_t)(112 * 1024 + 512) * 1024); // 64 KiB

    ctxT_kernel<<<dim3(D / 64, LS / 64, B), 256, 0, stream>>>(ctx, ctxT);
    wconv_kernel<<<dim3(SD * D / (256 * 8)), 256, 0, stream>>>(W, Wb);
    gemm1_kernel<<<dim3(512), 256, 0, stream>>>(query, mat, ctx, attn);
    mid_kernel<<<dim3(B), 512, 0, stream>>>(attn, ctxT, smooth, wctx, invq);
    gemm3_kernel<<<dim3(LQ / 64, B), 512, 0, stream>>>(wctx, query, invq, Wb, bias, out);
}

// Round 5
// 189.607 us; speedup vs baseline: 2.6436x; 1.2169x over previous
//
#include <hip/hip_runtime.h>
#include <hip/hip_bf16.h>

constexpr int B  = 128;
constexpr int LQ = 128;
constexpr int LS = 256;
constexpr int D  = 1024;
constexpr int SD = 256;
constexpr float EPS = 1e-8f;

typedef __attribute__((ext_vector_type(8))) __bf16 bf16x8;
typedef __attribute__((ext_vector_type(4))) float f32x4;

__device__ inline ushort f2bf(float f) {
    union { float f; uint u; } v{f};
    uint r = v.u + 0x7fffu + ((v.u >> 16) & 1u);   // RNE
    return (ushort)(r >> 16);
}
__device__ inline float bf2f(ushort u) {
    union { uint u; float f; } v{(uint)u << 16};
    return v.f;
}
__device__ inline uint4 pack8(float4 a, float4 b) {
    union { ushort us[8]; uint4 u4; } r;
    r.us[0]=f2bf(a.x); r.us[1]=f2bf(a.y); r.us[2]=f2bf(a.z); r.us[3]=f2bf(a.w);
    r.us[4]=f2bf(b.x); r.us[5]=f2bf(b.y); r.us[6]=f2bf(b.z); r.us[7]=f2bf(b.w);
    return r.u4;
}
// 128B-row LDS tiles (64 bf16): XOR-swizzle bank fix
__device__ inline int swz(int row, int kbyte) {
    return row * 128 + (kbyte ^ ((row & 7) << 4));
}
__device__ inline bf16x8 lds_frag(const ushort* base, int row, int kk, int lane) {
    int kbyte = kk * 64 + (lane >> 4) * 16;
    return *(const bf16x8*)((const char*)base + swz(row, kbyte));
}
// 512B-row LDS tiles (256 bf16): same XOR pattern
__device__ inline int swz512(int row, int kbyte) {
    return row * 512 + (kbyte ^ ((row & 7) << 4));
}
__device__ inline f32x4 mfma16(bf16x8 a, bf16x8 b, f32x4 c) {
    return __builtin_amdgcn_mfma_f32_16x16x32_bf16(a, b, c, 0, 0, 0);
}

// =====================================================================
// ctxT[b][d][s] (bf16) <- transpose+convert ctx[b][s][d] fp32. 64x64 tiles.
// =====================================================================
__global__ __launch_bounds__(256) void ctxT_kernel(
    const float* __restrict__ ctx, ushort* __restrict__ ctxT)
{
    const int b = blockIdx.z, d0 = blockIdx.x * 64, s0 = blockIdx.y * 64;
    __shared__ ushort T[64][72];   // T[d][s]
    const int t = threadIdx.x;
    const float* src = ctx + ((size_t)b * LS + s0) * D + d0;
    const int r = t >> 4;
    const int c = (t & 15) * 4;
#pragma unroll
    for (int p = 0; p < 4; ++p) {
        float4 v = *(const float4*)(src + (size_t)(r + p * 16) * D + c);
        T[c + 0][r + p * 16] = f2bf(v.x);
        T[c + 1][r + p * 16] = f2bf(v.y);
        T[c + 2][r + p * 16] = f2bf(v.z);
        T[c + 3][r + p * 16] = f2bf(v.w);
    }
    __syncthreads();
    ushort* dst = ctxT + ((size_t)b * D + d0) * LS + s0;
    const int rd = t >> 3;
    const int sc = (t & 7) * 8;
#pragma unroll
    for (int p = 0; p < 2; ++p) {
        uint4 o = *(const uint4*)&T[rd + p * 32][sc];
        *(uint4*)(dst + (size_t)(rd + p * 32) * LS + sc) = o;
    }
}

// =====================================================================
// Wb (bf16) <- W fp32
// =====================================================================
__global__ __launch_bounds__(256) void wconv_kernel(
    const float* __restrict__ W, ushort* __restrict__ Wb)
{
    size_t i = ((size_t)blockIdx.x * 256 + threadIdx.x) * 8;
    float4 a = *(const float4*)(W + i);
    float4 b = *(const float4*)(W + i + 4);
    *(uint4*)(Wb + i) = pack8(a, b);
}

// =====================================================================
// attn_kernel: one block per batch. 512 thr (8 waves), 134 KB LDS.
//   phase A: S = leaky( (q.*m) . ctx^T )  -- acc 128x256 f32 in registers
//   phase B: col-l2norm (over q) + softmax (over s) in registers,
//            P bf16 -> LDS
//   phase C: wctx = P . ctxT^T (PV), rowss -> invq
// =====================================================================
__global__ __launch_bounds__(512) void attn_kernel(
    const float* __restrict__ query, const float* __restrict__ mat,
    const float* __restrict__ ctx, const ushort* __restrict__ ctxT,
    const int* __restrict__ smooth_p, ushort* __restrict__ wctx,
    float* __restrict__ invq)
{
    const int b = blockIdx.x;
    __shared__ ushort P[128 * 256];       // 64 KB, swz512 rows
    __shared__ ushort Stage[32 * 1024];   // 64 KB: A[128*64]@0 + B[256*64]@8192 ; PV Bs[128*256]
    __shared__ float colss[2][256];
    __shared__ float redA[4][128];
    __shared__ float rowss[128][4];

    const int t = threadIdx.x;
    const int wv = t >> 6, l = t & 63;

    if (t < 512) rowss[t >> 2][t & 3] = 0.f;

    // ---------------- phase A: QK gemm ----------------
    const int wq = wv >> 2, ws = wv & 3;          // wave tile: 64q x 64s
    const float* Qb = query + (size_t)b * LQ * D;
    const float* Mb = mat   + (size_t)b * LQ * D;
    const float* Cb = ctx   + (size_t)b * LS * D;

    const int r0 = t >> 3, k8 = (t & 7) * 8;

    f32x4 acc[4][4] = {};
    float4 aq[4], am[4];   // A rows r0, r0+64
    float4 brg[8];         // B rows r0 + j*64

    // prologue: load tile 0
#pragma unroll
    for (int h = 0; h < 2; ++h) {
        const float* qp = Qb + (size_t)(r0 + h * 64) * D + k8;
        const float* mp = Mb + (size_t)(r0 + h * 64) * D + k8;
        aq[h*2] = *(const float4*)qp; aq[h*2+1] = *(const float4*)(qp + 4);
        am[h*2] = *(const float4*)mp; am[h*2+1] = *(const float4*)(mp + 4);
    }
#pragma unroll
    for (int j = 0; j < 4; ++j) {
        const float* cp = Cb + (size_t)(r0 + j * 64) * D + k8;
        brg[j*2] = *(const float4*)cp; brg[j*2+1] = *(const float4*)(cp + 4);
    }

#pragma unroll 1
    for (int ks = 0; ks < 16; ++ks) {
        // pack + LDS store of current tile
#pragma unroll
        for (int h = 0; h < 2; ++h) {
            float4 p1{aq[h*2].x*am[h*2].x, aq[h*2].y*am[h*2].y,
                      aq[h*2].z*am[h*2].z, aq[h*2].w*am[h*2].w};
            float4 p2{aq[h*2+1].x*am[h*2+1].x, aq[h*2+1].y*am[h*2+1].y,
                      aq[h*2+1].z*am[h*2+1].z, aq[h*2+1].w*am[h*2+1].w};
            *(uint4*)((char*)Stage + swz(r0 + h * 64, k8 * 2)) = pack8(p1, p2);
        }
#pragma unroll
        for (int j = 0; j < 4; ++j)
            *(uint4*)((char*)Stage + 16384 + swz(r0 + j * 64, k8 * 2)) = pack8(brg[j*2], brg[j*2+1]);
        __syncthreads();
        // issue next-tile loads (overlap with MFMA)
        if (ks < 15) {
            const int k0 = (ks + 1) * 64;
#pragma unroll
            for (int h = 0; h < 2; ++h) {
                const float* qp = Qb + (size_t)(r0 + h * 64) * D + k0 + k8;
                const float* mp = Mb + (size_t)(r0 + h * 64) * D + k0 + k8;
                aq[h*2] = *(const float4*)qp; aq[h*2+1] = *(const float4*)(qp + 4);
                am[h*2] = *(const float4*)mp; am[h*2+1] = *(const float4*)(mp + 4);
            }
#pragma unroll
            for (int j = 0; j < 4; ++j) {
                const float* cp = Cb + (size_t)(r0 + j * 64) * D + k0 + k8;
                brg[j*2] = *(const float4*)cp; brg[j*2+1] = *(const float4*)(cp + 4);
            }
        }
#pragma unroll
        for (int kk = 0; kk < 2; ++kk) {
            bf16x8 af[4], bfr[4];
#pragma unroll
            for (int i = 0; i < 4; ++i)
                af[i] = lds_frag(Stage, wq * 64 + i * 16 + (l & 15), kk, l);
#pragma unroll
            for (int n = 0; n < 4; ++n)
                bfr[n] = lds_frag(Stage + 8192, ws * 64 + n * 16 + (l & 15), kk, l);
#pragma unroll
            for (int i = 0; i < 4; ++i)
#pragma unroll
                for (int n = 0; n < 4; ++n) acc[i][n] = mfma16(af[i], bfr[n], acc[i][n]);
        }
        __syncthreads();
    }

    // ---------------- phase B: leaky + col-l2norm + softmax -> P ----------------
    // leaky + column (over q) sumsq partials
#pragma unroll
    for (int n = 0; n < 4; ++n) {
        float cp_ = 0.f;
#pragma unroll
        for (int i = 0; i < 4; ++i)
#pragma unroll
            for (int r = 0; r < 4; ++r) {
                float v = acc[i][n][r];
                v = v >= 0.f ? v : 0.1f * v;
                acc[i][n][r] = v;
                cp_ += v * v;
            }
        cp_ += __shfl_xor(cp_, 16);
        cp_ += __shfl_xor(cp_, 32);
        if ((l >> 4) == 0) colss[wq][ws * 64 + n * 16 + l] = cp_;
    }
    __syncthreads();
    if (t < 256) colss[0][t] = 1.0f / (sqrtf(colss[0][t] + colss[1][t]) + EPS);
    __syncthreads();

    const float sm = (float)(*smooth_p);
    float invs[4];
#pragma unroll
    for (int n = 0; n < 4; ++n) invs[n] = colss[0][ws * 64 + n * 16 + (l & 15)] * sm;

    float red16[4][4];   // per (i,r) scratch
    // x = v*invs ; per-wave row max (over n and l&15)
#pragma unroll
    for (int i = 0; i < 4; ++i)
#pragma unroll
        for (int r = 0; r < 4; ++r) {
            float mx = -1e30f;
#pragma unroll
            for (int n = 0; n < 4; ++n) {
                float x = acc[i][n][r] * invs[n];
                acc[i][n][r] = x;
                mx = fmaxf(mx, x);
            }
            mx = fmaxf(mx, __shfl_xor(mx, 1));
            mx = fmaxf(mx, __shfl_xor(mx, 2));
            mx = fmaxf(mx, __shfl_xor(mx, 4));
            mx = fmaxf(mx, __shfl_xor(mx, 8));
            red16[i][r] = mx;
        }
    if ((l & 15) == 0) {
#pragma unroll
        for (int i = 0; i < 4; ++i)
#pragma unroll
            for (int r = 0; r < 4; ++r)
                redA[ws][wq * 64 + i * 16 + (l >> 4) * 4 + r] = red16[i][r];
    }
    __syncthreads();
    if (t < 128)
        redA[0][t] = fmaxf(fmaxf(redA[0][t], redA[1][t]), fmaxf(redA[2][t], redA[3][t]));
    __syncthreads();

    // exp + per-wave row sum
#pragma unroll
    for (int i = 0; i < 4; ++i)
#pragma unroll
        for (int r = 0; r < 4; ++r) {
            float mx = redA[0][wq * 64 + i * 16 + (l >> 4) * 4 + r];
            float s_ = 0.f;
#pragma unroll
            for (int n = 0; n < 4; ++n) {
                float e = __expf(acc[i][n][r] - mx);
                acc[i][n][r] = e;
                s_ += e;
            }
            s_ += __shfl_xor(s_, 1);
            s_ += __shfl_xor(s_, 2);
            s_ += __shfl_xor(s_, 4);
            s_ += __shfl_xor(s_, 8);
            red16[i][r] = s_;
        }
    __syncthreads();   // all max reads done before overwriting redA
    if ((l & 15) == 0) {
#pragma unroll
        for (int i = 0; i < 4; ++i)
#pragma unroll
            for (int r = 0; r < 4; ++r)
                redA[ws][wq * 64 + i * 16 + (l >> 4) * 4 + r] = red16[i][r];
    }
    __syncthreads();
    if (t < 128)
        redA[0][t] = 1.0f / (redA[0][t] + redA[1][t] + redA[2][t] + redA[3][t]);
    __syncthreads();

    // P = e * rs -> bf16 -> LDS
#pragma unroll
    for (int i = 0; i < 4; ++i)
#pragma unroll
        for (int r = 0; r < 4; ++r) {
            int row = wq * 64 + i * 16 + (l >> 4) * 4 + r;
            float rs = redA[0][row];
#pragma unroll
            for (int n = 0; n < 4; ++n) {
                int col = ws * 64 + n * 16 + (l & 15);
                *(ushort*)((char*)P + swz512(row, col * 2)) = f2bf(acc[i][n][r] * rs);
            }
        }

    // ---------------- phase C: PV gemm ----------------
    const ushort* CTb = ctxT + (size_t)b * D * LS;
    const int wq2 = wv >> 2, wd = wv & 3;
    const int cc = t & 31, rr = t >> 5;
#pragma unroll 1
    for (int dt = 0; dt < 8; ++dt) {
        __syncthreads();   // P ready (dt=0) / Stage free (dt>0)
#pragma unroll
        for (int it = 0; it < 8; ++it) {
            int row = rr + it * 16;
            uint4 v = *(const uint4*)(CTb + (size_t)(dt * 128 + row) * LS + cc * 8);
            *(uint4*)((char*)Stage + swz512(row, cc * 16)) = v;
        }
        __syncthreads();
        f32x4 a2[4][2] = {};
#pragma unroll
        for (int kk = 0; kk < 8; ++kk) {
            bf16x8 af[4], bfr[2];
            int kb = kk * 64 + (l >> 4) * 16;
#pragma unroll
            for (int i = 0; i < 4; ++i)
                af[i] = *(const bf16x8*)((const char*)P + swz512(wq2 * 64 + i * 16 + (l & 15), kb));
#pragma unroll
            for (int n = 0; n < 2; ++n)
                bfr[n] = *(const bf16x8*)((const char*)Stage + swz512(wd * 32 + n * 16 + (l & 15), kb));
#pragma unroll
            for (int i = 0; i < 4; ++i)
#pragma unroll
                for (int n = 0; n < 2; ++n) a2[i][n] = mfma16(af[i], bfr[n], a2[i][n]);
        }
        ushort* Ob = wctx + (size_t)b * LQ * D + dt * 128 + wd * 32;
#pragma unroll
        for (int i = 0; i < 4; ++i)
#pragma unroll
            for (int r = 0; r < 4; ++r) {
                int row = wq2 * 64 + i * 16 + (l >> 4) * 4 + r;
                float p2 = a2[i][0][r] * a2[i][0][r] + a2[i][1][r] * a2[i][1][r];
#pragma unroll
                for (int off = 1; off < 16; off <<= 1) p2 += __shfl_xor(p2, off);
                if ((l & 15) == 0) rowss[row][wd] += p2;
                Ob[(size_t)row * D + (l & 15)]      = f2bf(a2[i][0][r]);
                Ob[(size_t)row * D + 16 + (l & 15)] = f2bf(a2[i][1][r]);
            }
    }
    __syncthreads();
    if (t < 128) {
        float s4 = rowss[t][0] + rowss[t][1] + rowss[t][2] + rowss[t][3];
        invq[(size_t)b * LQ + t] = 1.0f / (sqrtf(s4) + EPS);
    }
}

// =====================================================================
// gemm3+finalnorm: out[b][q][k] = l2norm_k( sum_d sr[q][d]*Wb[k][d] + b[k] )
// sr computed on the fly: (query - wctx*invq)^2.
// BM=64(q) BN=256 BK=64. 512 thr, 8 waves 2x4.
// =====================================================================
__global__ __launch_bounds__(512) void gemm3_kernel(
    const ushort* __restrict__ wctx, const float* __restrict__ query,
    const float* __restrict__ invq, const ushort* __restrict__ Wb,
    const float* __restrict__ bias, float* __restrict__ out)
{
    const int m0 = blockIdx.x * 64;
    const int b  = blockIdx.y;
    __shared__ ushort As[64 * 64];
    __shared__ ushort Bs[256 * 64];
    __shared__ float red[64][4];
    __shared__ float invr[64];
    const int t = threadIdx.x;
    const int w = t >> 6, l = t & 63;
    const int wm = (w >> 2) * 32, wn = (w & 3) * 64;

    const int arow = t >> 3, ako = (t & 7) * 8;
    const float  ivq = invq[(size_t)b * LQ + m0 + arow];
    const float* Qp  = query + ((size_t)b * LQ + m0 + arow) * D + ako;
    const ushort* Wp = wctx  + ((size_t)b * LQ + m0 + arow) * D + ako;

    f32x4 acc[2][4] = {};

    for (int k0 = 0; k0 < D; k0 += 64) {
        if (k0) __syncthreads();
        {   // A: sr on the fly
            uint4 wu = *(const uint4*)(Wp + k0);
            float4 q1 = *(const float4*)(Qp + k0);
            float4 q2 = *(const float4*)(Qp + k0 + 4);
            float d0 = q1.x - bf2f((ushort)(wu.x & 0xffff)) * ivq;
            float d1 = q1.y - bf2f((ushort)(wu.x >> 16))    * ivq;
            float d2 = q1.z - bf2f((ushort)(wu.y & 0xffff)) * ivq;
            float d3 = q1.w - bf2f((ushort)(wu.y >> 16))    * ivq;
            float d4 = q2.x - bf2f((ushort)(wu.z & 0xffff)) * ivq;
            float d5 = q2.y - bf2f((ushort)(wu.z >> 16))    * ivq;
            float d6 = q2.z - bf2f((ushort)(wu.w & 0xffff)) * ivq;
            float d7 = q2.w - bf2f((ushort)(wu.w >> 16))    * ivq;
            float4 s1{d0*d0, d1*d1, d2*d2, d3*d3};
            float4 s2{d4*d4, d5*d5, d6*d6, d7*d7};
            *(uint4*)((char*)As + swz(arow, ako * 2)) = pack8(s1, s2);
        }
#pragma unroll
        for (int j = 0; j < 4; ++j) {   // B: Wb
            int c = t + j * 512;
            int row = c >> 3, ko = (c & 7) * 8;
            *(uint4*)((char*)Bs + swz(row, ko * 2)) =
                *(const uint4*)(Wb + (size_t)row * D + k0 + ko);
        }
        __syncthreads();
#pragma unroll
        for (int kk = 0; kk < 2; ++kk) {
            bf16x8 af[2], bfr[4];
#pragma unroll
            for (int i = 0; i < 2; ++i) af[i] = lds_frag(As, wm + i * 16 + (l & 15), kk, l);
#pragma unroll
            for (int n = 0; n < 4; ++n) bfr[n] = lds_frag(Bs, wn + n * 16 + (l & 15), kk, l);
#pragma unroll
            for (int i = 0; i < 2; ++i)
#pragma unroll
                for (int n = 0; n < 4; ++n) acc[i][n] = mfma16(af[i], bfr[n], acc[i][n]);
        }
    }
#pragma unroll
    for (int n = 0; n < 4; ++n) {
        float bv = bias[wn + n * 16 + (l & 15)];
#pragma unroll
        for (int i = 0; i < 2; ++i)
#pragma unroll
            for (int r = 0; r < 4; ++r) acc[i][n][r] += bv;
    }
#pragma unroll
    for (int i = 0; i < 2; ++i)
#pragma unroll
        for (int r = 0; r < 4; ++r) {
            float p = 0.f;
#pragma unroll
            for (int n = 0; n < 4; ++n) p += acc[i][n][r] * acc[i][n][r];
#pragma unroll
            for (int off = 1; off < 16; off <<= 1) p += __shfl_xor(p, off);
            int rowl = wm + i * 16 + (l >> 4) * 4 + r;
            if ((l & 15) == 0) red[rowl][w & 3] = p;
        }
    __syncthreads();
    if (t < 64) {
        float s = red[t][0] + red[t][1] + red[t][2] + red[t][3];
        invr[t] = 1.0f / (sqrtf(s) + EPS);
    }
    __syncthreads();
    float* Ob = out + ((size_t)b * LQ + m0) * SD;
#pragma unroll
    for (int i = 0; i < 2; ++i)
#pragma unroll
        for (int r = 0; r < 4; ++r) {
            int rowl = wm + i * 16 + (l >> 4) * 4 + r;
            float iv = invr[rowl];
#pragma unroll
            for (int n = 0; n < 4; ++n) {
                int col = wn + n * 16 + (l & 15);
                Ob[(size_t)rowl * SD + col] = acc[i][n][r] * iv;
            }
        }
}

// =====================================================================
extern "C" void kernel_launch(void* const* d_in, const int* in_sizes, int n_in,
                              void* d_out, int out_size, void* d_ws, size_t ws_size,
                              hipStream_t stream)
{
    const float* query  = (const float*)d_in[0];
    const float* ctx    = (const float*)d_in[1];
    const float* mat    = (const float*)d_in[2];
    const float* W      = (const float*)d_in[3];
    const float* bias   = (const float*)d_in[4];
    const int*   smooth = (const int*)d_in[5];
    float* out = (float*)d_out;

    char* ws = (char*)d_ws;
    ushort* wctx = (ushort*)ws;                                  // 32 MiB
    ushort* ctxT = (ushort*)(ws + (size_t)32 * 1024 * 1024);     // 64 MiB
    ushort* Wb   = (ushort*)(ws + (size_t)96 * 1024 * 1024);     // 0.5 MiB
    float*  invq = (float*)(ws + (size_t)(96 * 1024 + 512) * 1024); // 64 KiB

    ctxT_kernel<<<dim3(D / 64, LS / 64, B), 256, 0, stream>>>(ctx, ctxT);
    wconv_kernel<<<dim3(SD * D / (256 * 8)), 256, 0, stream>>>(W, Wb);
    attn_kernel<<<dim3(B), 512, 0, stream>>>(query, mat, ctx, ctxT, smooth, wctx, invq);
    gemm3_kernel<<<dim3(LQ / 64, B), 512, 0, stream>>>(wctx, query, invq, Wb, bias, out);
}

// Round 6
// 179.662 us; speedup vs baseline: 2.7899x; 1.0554x over previous
//
#include <hip/hip_runtime.h>
#include <hip/hip_bf16.h>

constexpr int B  = 128;
constexpr int LQ = 128;
constexpr int LS = 256;
constexpr int D  = 1024;
constexpr int SD = 256;
constexpr float EPS = 1e-8f;

typedef __attribute__((ext_vector_type(8))) __bf16 bf16x8;
typedef __attribute__((ext_vector_type(4))) float f32x4;

__device__ inline ushort f2bf(float f) {
    union { float f; uint u; } v{f};
    uint r = v.u + 0x7fffu + ((v.u >> 16) & 1u);   // RNE
    return (ushort)(r >> 16);
}
__device__ inline float bf2f(ushort u) {
    union { uint u; float f; } v{(uint)u << 16};
    return v.f;
}
__device__ inline uint4 pack8(float4 a, float4 b) {
    union { ushort us[8]; uint4 u4; } r;
    r.us[0]=f2bf(a.x); r.us[1]=f2bf(a.y); r.us[2]=f2bf(a.z); r.us[3]=f2bf(a.w);
    r.us[4]=f2bf(b.x); r.us[5]=f2bf(b.y); r.us[6]=f2bf(b.z); r.us[7]=f2bf(b.w);
    return r.u4;
}
// 128B-row LDS tiles (64 bf16): XOR-swizzle bank fix
__device__ inline int swz(int row, int kbyte) {
    return row * 128 + (kbyte ^ ((row & 7) << 4));
}
__device__ inline bf16x8 lds_frag(const ushort* base, int row, int kk, int lane) {
    int kbyte = kk * 64 + (lane >> 4) * 16;
    return *(const bf16x8*)((const char*)base + swz(row, kbyte));
}
// 512B-row LDS tiles (256 bf16): same XOR pattern
__device__ inline int swz512(int row, int kbyte) {
    return row * 512 + (kbyte ^ ((row & 7) << 4));
}
__device__ inline f32x4 mfma16(bf16x8 a, bf16x8 b, f32x4 c) {
    return __builtin_amdgcn_mfma_f32_16x16x32_bf16(a, b, c, 0, 0, 0);
}

// =====================================================================
// ctxT[b][d][s] (bf16) <- transpose+convert ctx[b][s][d] fp32. 64x64 tiles.
// =====================================================================
__global__ __launch_bounds__(256) void ctxT_kernel(
    const float* __restrict__ ctx, ushort* __restrict__ ctxT)
{
    const int b = blockIdx.z, d0 = blockIdx.x * 64, s0 = blockIdx.y * 64;
    __shared__ ushort T[64][72];   // T[d][s]
    const int t = threadIdx.x;
    const float* src = ctx + ((size_t)b * LS + s0) * D + d0;
    const int r = t >> 4;
    const int c = (t & 15) * 4;
#pragma unroll
    for (int p = 0; p < 4; ++p) {
        float4 v = *(const float4*)(src + (size_t)(r + p * 16) * D + c);
        T[c + 0][r + p * 16] = f2bf(v.x);
        T[c + 1][r + p * 16] = f2bf(v.y);
        T[c + 2][r + p * 16] = f2bf(v.z);
        T[c + 3][r + p * 16] = f2bf(v.w);
    }
    __syncthreads();
    ushort* dst = ctxT + ((size_t)b * D + d0) * LS + s0;
    const int rd = t >> 3;
    const int sc = (t & 7) * 8;
#pragma unroll
    for (int p = 0; p < 2; ++p) {
        uint4 o = *(const uint4*)&T[rd + p * 32][sc];
        *(uint4*)(dst + (size_t)(rd + p * 32) * LS + sc) = o;
    }
}

// =====================================================================
// Wb (bf16) <- W fp32
// =====================================================================
__global__ __launch_bounds__(256) void wconv_kernel(
    const float* __restrict__ W, ushort* __restrict__ Wb)
{
    size_t i = ((size_t)blockIdx.x * 256 + threadIdx.x) * 8;
    float4 a = *(const float4*)(W + i);
    float4 b = *(const float4*)(W + i + 4);
    *(uint4*)(Wb + i) = pack8(a, b);
}

// =====================================================================
// qm (bf16) = query * matrix   (streaming, 8 elems/thread)
// =====================================================================
__global__ __launch_bounds__(256) void qm_kernel(
    const float* __restrict__ query, const float* __restrict__ mat,
    ushort* __restrict__ qm)
{
    size_t i = ((size_t)blockIdx.x * 256 + threadIdx.x) * 8;
    float4 q1 = *(const float4*)(query + i), q2 = *(const float4*)(query + i + 4);
    float4 m1 = *(const float4*)(mat + i),   m2 = *(const float4*)(mat + i + 4);
    float4 p1{q1.x*m1.x, q1.y*m1.y, q1.z*m1.z, q1.w*m1.w};
    float4 p2{q2.x*m2.x, q2.y*m2.y, q2.z*m2.z, q2.w*m2.w};
    *(uint4*)(qm + i) = pack8(p1, p2);
}

// =====================================================================
// gemmA: S = leaky( qm[128q][1024d] . ctx[64s][1024d]^T ), col-l2norm over
// q (full 128 within block), E = exp(S*inv*smooth) bf16 -> global.
// Grid 512 = (b x 4 s-tiles), XCD-swizzled. 512 thr, 8 waves 2q x 4s.
// BM=128 BN=64 BK=64, double-buffered LDS (48 KB).
// No softmax max-pass needed: |x| <= smooth after l2norm.
// =====================================================================
__global__ __launch_bounds__(512) void gemmA_kernel(
    const ushort* __restrict__ qm, const float* __restrict__ ctx,
    const int* __restrict__ smooth_p, ushort* __restrict__ E)
{
    const int bid = blockIdx.x;
    const int xcd = bid & 7, idx = bid >> 3;
    const int b  = xcd * 16 + (idx >> 2);
    const int n0 = (idx & 3) * 64;        // s-offset
    __shared__ ushort As[2][128 * 64];
    __shared__ ushort Bs[2][64 * 64];
    __shared__ float colssP[2][64];
    __shared__ float invsm[64];
    const int t = threadIdx.x;
    const int wv = t >> 6, l = t & 63;
    const int wq = wv >> 2, wsv = wv & 3;

    const ushort* Ab = qm  + (size_t)b * LQ * D;
    const float*  Cb = ctx + ((size_t)b * LS + n0) * D;
    const int r0 = t >> 3, k8 = (t & 7) * 8;

    f32x4 acc[4] = {};
    uint4 a0, a1;
    float4 b0, b1;

    // prologue: stage tile 0
    a0 = *(const uint4*)(Ab + (size_t)r0 * D + k8);
    a1 = *(const uint4*)(Ab + (size_t)(r0 + 64) * D + k8);
    b0 = *(const float4*)(Cb + (size_t)r0 * D + k8);
    b1 = *(const float4*)(Cb + (size_t)r0 * D + k8 + 4);
    *(uint4*)((char*)As[0] + swz(r0, k8 * 2))      = a0;
    *(uint4*)((char*)As[0] + swz(r0 + 64, k8 * 2)) = a1;
    *(uint4*)((char*)Bs[0] + swz(r0, k8 * 2))      = pack8(b0, b1);
    __syncthreads();

    int cur = 0;
#pragma unroll 1
    for (int ks = 0; ks < 15; ++ks) {
        const int k0 = (ks + 1) * 64;
        a0 = *(const uint4*)(Ab + (size_t)r0 * D + k0 + k8);
        a1 = *(const uint4*)(Ab + (size_t)(r0 + 64) * D + k0 + k8);
        b0 = *(const float4*)(Cb + (size_t)r0 * D + k0 + k8);
        b1 = *(const float4*)(Cb + (size_t)r0 * D + k0 + k8 + 4);
#pragma unroll
        for (int kk = 0; kk < 2; ++kk) {
            bf16x8 bfr = lds_frag(Bs[cur], wsv * 16 + (l & 15), kk, l);
#pragma unroll
            for (int i = 0; i < 4; ++i) {
                bf16x8 af = lds_frag(As[cur], wq * 64 + i * 16 + (l & 15), kk, l);
                acc[i] = mfma16(af, bfr, acc[i]);
            }
        }
        *(uint4*)((char*)As[cur ^ 1] + swz(r0, k8 * 2))      = a0;
        *(uint4*)((char*)As[cur ^ 1] + swz(r0 + 64, k8 * 2)) = a1;
        *(uint4*)((char*)Bs[cur ^ 1] + swz(r0, k8 * 2))      = pack8(b0, b1);
        __syncthreads();
        cur ^= 1;
    }
#pragma unroll
    for (int kk = 0; kk < 2; ++kk) {
        bf16x8 bfr = lds_frag(Bs[cur], wsv * 16 + (l & 15), kk, l);
#pragma unroll
        for (int i = 0; i < 4; ++i) {
            bf16x8 af = lds_frag(As[cur], wq * 64 + i * 16 + (l & 15), kk, l);
            acc[i] = mfma16(af, bfr, acc[i]);
        }
    }

    // epilogue: leaky + column sumsq (over all 128 q) -> invsm -> E=exp
    float csum = 0.f;
#pragma unroll
    for (int i = 0; i < 4; ++i)
#pragma unroll
        for (int r = 0; r < 4; ++r) {
            float v = acc[i][r];
            v = v >= 0.f ? v : 0.1f * v;
            acc[i][r] = v;
            csum += v * v;
        }
    csum += __shfl_xor(csum, 16);
    csum += __shfl_xor(csum, 32);
    if (l < 16) colssP[wq][wsv * 16 + l] = csum;
    __syncthreads();
    const float sm = (float)(*smooth_p);
    if (t < 64) invsm[t] = sm / (sqrtf(colssP[0][t] + colssP[1][t]) + EPS);
    __syncthreads();
    const float invc = invsm[wsv * 16 + (l & 15)];
    ushort* Eb = E + (size_t)b * LQ * LS + n0 + wsv * 16 + (l & 15);
#pragma unroll
    for (int i = 0; i < 4; ++i)
#pragma unroll
        for (int r = 0; r < 4; ++r) {
            int row = wq * 64 + i * 16 + (l >> 4) * 4 + r;
            Eb[(size_t)row * LS] = f2bf(__expf(acc[i][r] * invc));
        }
}

// =====================================================================
// pv: wctx[64q][512d] = (E . ctxT^T) * (1/rowsum(E)); rowss partials.
// Grid 512 = (b x 2 qh x 2 dh), XCD-swizzled. 512 thr, 8 waves 2q x 4d.
// E staged once (32 KB LDS), A-frags hoisted to registers; B tiles
// single-buffered (32 KB) -> 2 blocks/CU.
// =====================================================================
__global__ __launch_bounds__(512) void pv_kernel(
    const ushort* __restrict__ E, const ushort* __restrict__ ctxT,
    ushort* __restrict__ wctx, float* __restrict__ rowssP)
{
    const int bid = blockIdx.x;
    const int xcd = bid & 7, idx = bid >> 3;
    const int b  = xcd * 16 + (idx >> 2);
    const int qh = (idx >> 1) & 1, dh = idx & 1;
    __shared__ ushort Es[64 * 256];    // swz512
    __shared__ ushort Bs[64 * 256];    // swz512
    __shared__ float rsumL[64];
    __shared__ float rinv[64];
    __shared__ float rowssL[64][4];
    const int t = threadIdx.x;
    const int wv = t >> 6, l = t & 63;
    const int wq = wv >> 2, wd = wv & 3;
    const int cc = t & 31, rr = t >> 5;   // staging coords

    // stage E (64q x 256s) + per-row exp-sums
    const ushort* Eb = E + ((size_t)b * LQ + qh * 64) * LS;
    float part[4];
#pragma unroll
    for (int it = 0; it < 4; ++it) {
        int row = rr + it * 16;
        uint4 v = *(const uint4*)(Eb + (size_t)row * LS + cc * 8);
        *(uint4*)((char*)Es + swz512(row, cc * 16)) = v;
        const ushort* us = (const ushort*)&v;
        float s = 0.f;
#pragma unroll
        for (int j = 0; j < 8; ++j) s += bf2f(us[j]);
        part[it] = s;
    }
    if (t < 256) rowssL[t >> 2][t & 3] = 0.f;
#pragma unroll
    for (int it = 0; it < 4; ++it) {
        float s = part[it];
        s += __shfl_xor(s, 1);  s += __shfl_xor(s, 2);
        s += __shfl_xor(s, 4);  s += __shfl_xor(s, 8);
        s += __shfl_xor(s, 16);
        if ((l & 31) == 0) rsumL[rr + it * 16] = s;
    }
    __syncthreads();
    if (t < 64) rinv[t] = 1.0f / rsumL[t];
    __syncthreads();

    // hoist A-fragments (reused across all 8 d-tiles)
    bf16x8 af[2][8];
#pragma unroll
    for (int i = 0; i < 2; ++i)
#pragma unroll
        for (int kk = 0; kk < 8; ++kk)
            af[i][kk] = *(const bf16x8*)((const char*)Es +
                swz512(wq * 32 + i * 16 + (l & 15), kk * 64 + (l >> 4) * 16));

    const ushort* Cb = ctxT + ((size_t)b * D + dh * 512) * LS;
    ushort* Ob = wctx + ((size_t)b * LQ + qh * 64) * D + dh * 512;

#pragma unroll 1
    for (int dt = 0; dt < 8; ++dt) {
        __syncthreads();   // Bs free
#pragma unroll
        for (int it = 0; it < 4; ++it) {
            int row = rr + it * 16;
            uint4 v = *(const uint4*)(Cb + (size_t)(dt * 64 + row) * LS + cc * 8);
            *(uint4*)((char*)Bs + swz512(row, cc * 16)) = v;
        }
        __syncthreads();
        f32x4 acc[2] = {};
#pragma unroll
        for (int kk = 0; kk < 8; ++kk) {
            bf16x8 bfr = *(const bf16x8*)((const char*)Bs +
                swz512(wd * 16 + (l & 15), kk * 64 + (l >> 4) * 16));
            acc[0] = mfma16(af[0][kk], bfr, acc[0]);
            acc[1] = mfma16(af[1][kk], bfr, acc[1]);
        }
#pragma unroll
        for (int i = 0; i < 2; ++i)
#pragma unroll
            for (int r = 0; r < 4; ++r) {
                int row = wq * 32 + i * 16 + (l >> 4) * 4 + r;
                float wval = acc[i][r] * rinv[row];
                float p2 = wval * wval;
                p2 += __shfl_xor(p2, 1); p2 += __shfl_xor(p2, 2);
                p2 += __shfl_xor(p2, 4); p2 += __shfl_xor(p2, 8);
                if ((l & 15) == 0) rowssL[row][wd] += p2;
                Ob[(size_t)row * D + dt * 64 + wd * 16 + (l & 15)] = f2bf(wval);
            }
    }
    __syncthreads();
    if (t < 64)
        rowssP[(size_t)b * 256 + dh * 128 + qh * 64 + t] =
            rowssL[t][0] + rowssL[t][1] + rowssL[t][2] + rowssL[t][3];
}

// =====================================================================
// gemm3+finalnorm: out[b][q][k] = l2norm_k( sum_d sr[q][d]*Wb[k][d] + b[k] )
// sr on the fly: (query - wctx*invq)^2 with invq from rowssP halves.
// BM=64(q) BN=256 BK=64. 512 thr, 8 waves 2x4.
// =====================================================================
__global__ __launch_bounds__(512) void gemm3_kernel(
    const ushort* __restrict__ wctx, const float* __restrict__ query,
    const float* __restrict__ rowssP, const ushort* __restrict__ Wb,
    const float* __restrict__ bias, float* __restrict__ out)
{
    const int m0 = blockIdx.x * 64;
    const int b  = blockIdx.y;
    __shared__ ushort As[64 * 64];
    __shared__ ushort Bs[256 * 64];
    __shared__ float red[64][4];
    __shared__ float invr[64];
    const int t = threadIdx.x;
    const int w = t >> 6, l = t & 63;
    const int wm = (w >> 2) * 32, wn = (w & 3) * 64;

    const int arow = t >> 3, ako = (t & 7) * 8;
    const float r0v = rowssP[(size_t)b * 256 + m0 + arow];
    const float r1v = rowssP[(size_t)b * 256 + 128 + m0 + arow];
    const float ivq = 1.0f / (sqrtf(r0v + r1v) + EPS);
    const float* Qp  = query + ((size_t)b * LQ + m0 + arow) * D + ako;
    const ushort* Wp = wctx  + ((size_t)b * LQ + m0 + arow) * D + ako;

    f32x4 acc[2][4] = {};

    for (int k0 = 0; k0 < D; k0 += 64) {
        if (k0) __syncthreads();
        {   // A: sr on the fly
            uint4 wu = *(const uint4*)(Wp + k0);
            float4 q1 = *(const float4*)(Qp + k0);
            float4 q2 = *(const float4*)(Qp + k0 + 4);
            float d0 = q1.x - bf2f((ushort)(wu.x & 0xffff)) * ivq;
            float d1 = q1.y - bf2f((ushort)(wu.x >> 16))    * ivq;
            float d2 = q1.z - bf2f((ushort)(wu.y & 0xffff)) * ivq;
            float d3 = q1.w - bf2f((ushort)(wu.y >> 16))    * ivq;
            float d4 = q2.x - bf2f((ushort)(wu.z & 0xffff)) * ivq;
            float d5 = q2.y - bf2f((ushort)(wu.z >> 16))    * ivq;
            float d6 = q2.z - bf2f((ushort)(wu.w & 0xffff)) * ivq;
            float d7 = q2.w - bf2f((ushort)(wu.w >> 16))    * ivq;
            float4 s1{d0*d0, d1*d1, d2*d2, d3*d3};
            float4 s2{d4*d4, d5*d5, d6*d6, d7*d7};
            *(uint4*)((char*)As + swz(arow, ako * 2)) = pack8(s1, s2);
        }
#pragma unroll
        for (int j = 0; j < 4; ++j) {   // B: Wb
            int c = t + j * 512;
            int row = c >> 3, ko = (c & 7) * 8;
            *(uint4*)((char*)Bs + swz(row, ko * 2)) =
                *(const uint4*)(Wb + (size_t)row * D + k0 + ko);
        }
        __syncthreads();
#pragma unroll
        for (int kk = 0; kk < 2; ++kk) {
            bf16x8 af[2], bfr[4];
#pragma unroll
            for (int i = 0; i < 2; ++i) af[i] = lds_frag(As, wm + i * 16 + (l & 15), kk, l);
#pragma unroll
            for (int n = 0; n < 4; ++n) bfr[n] = lds_frag(Bs, wn + n * 16 + (l & 15), kk, l);
#pragma unroll
            for (int i = 0; i < 2; ++i)
#pragma unroll
                for (int n = 0; n < 4; ++n) acc[i][n] = mfma16(af[i], bfr[n], acc[i][n]);
        }
    }
#pragma unroll
    for (int n = 0; n < 4; ++n) {
        float bv = bias[wn + n * 16 + (l & 15)];
#pragma unroll
        for (int i = 0; i < 2; ++i)
#pragma unroll
            for (int r = 0; r < 4; ++r) acc[i][n][r] += bv;
    }
#pragma unroll
    for (int i = 0; i < 2; ++i)
#pragma unroll
        for (int r = 0; r < 4; ++r) {
            float p = 0.f;
#pragma unroll
            for (int n = 0; n < 4; ++n) p += acc[i][n][r] * acc[i][n][r];
#pragma unroll
            for (int off = 1; off < 16; off <<= 1) p += __shfl_xor(p, off);
            int rowl = wm + i * 16 + (l >> 4) * 4 + r;
            if ((l & 15) == 0) red[rowl][w & 3] = p;
        }
    __syncthreads();
    if (t < 64) {
        float s = red[t][0] + red[t][1] + red[t][2] + red[t][3];
        invr[t] = 1.0f / (sqrtf(s) + EPS);
    }
    __syncthreads();
    float* Ob = out + ((size_t)b * LQ + m0) * SD;
#pragma unroll
    for (int i = 0; i < 2; ++i)
#pragma unroll
        for (int r = 0; r < 4; ++r) {
            int rowl = wm + i * 16 + (l >> 4) * 4 + r;
            float iv = invr[rowl];
#pragma unroll
            for (int n = 0; n < 4; ++n) {
                int col = wn + n * 16 + (l & 15);
                Ob[(size_t)rowl * SD + col] = acc[i][n][r] * iv;
            }
        }
}

// =====================================================================
extern "C" void kernel_launch(void* const* d_in, const int* in_sizes, int n_in,
                              void* d_out, int out_size, void* d_ws, size_t ws_size,
                              hipStream_t stream)
{
    const float* query  = (const float*)d_in[0];
    const float* ctx    = (const float*)d_in[1];
    const float* mat    = (const float*)d_in[2];
    const float* W      = (const float*)d_in[3];
    const float* bias   = (const float*)d_in[4];
    const int*   smooth = (const int*)d_in[5];
    float* out = (float*)d_out;

    char* ws = (char*)d_ws;
    ushort* ctxT   = (ushort*)ws;                                   // 64 MiB
    ushort* qm     = (ushort*)(ws + (size_t)64 * 1024 * 1024);      // 32 MiB
    ushort* wctx   = qm;   // overlay: qm dead after gemmA, wctx written by pv
    ushort* E      = (ushort*)(ws + (size_t)96 * 1024 * 1024);      //  8 MiB
    ushort* Wb     = (ushort*)(ws + (size_t)104 * 1024 * 1024);     // 0.5 MiB
    float*  rowssP = (float*)(ws + (size_t)(104 * 1024 + 512) * 1024); // 128 KiB

    ctxT_kernel<<<dim3(D / 64, LS / 64, B), 256, 0, stream>>>(ctx, ctxT);
    wconv_kernel<<<dim3(SD * D / (256 * 8)), 256, 0, stream>>>(W, Wb);
    qm_kernel<<<dim3((size_t)B * LQ * D / (256 * 8)), 256, 0, stream>>>(query, mat, qm);
    gemmA_kernel<<<dim3(512), 512, 0, stream>>>(qm, ctx, smooth, E);
    pv_kernel<<<dim3(512), 512, 0, stream>>>(E, ctxT, wctx, rowssP);
    gemm3_kernel<<<dim3(2, B), 512, 0, stream>>>(wctx, query, rowssP, Wb, bias, out);
}

// Round 7
// 162.794 us; speedup vs baseline: 3.0790x; 1.1036x over previous
//
#include <hip/hip_runtime.h>
#include <hip/hip_bf16.h>

constexpr int B  = 128;
constexpr int LQ = 128;
constexpr int LS = 256;
constexpr int D  = 1024;
constexpr int SD = 256;
constexpr float EPS = 1e-8f;

typedef __attribute__((ext_vector_type(8))) __bf16 bf16x8;
typedef __attribute__((ext_vector_type(4))) float f32x4;

__device__ inline ushort f2bf(float f) {
    union { float f; uint u; } v{f};
    uint r = v.u + 0x7fffu + ((v.u >> 16) & 1u);   // RNE
    return (ushort)(r >> 16);
}
__device__ inline float bf2f(ushort u) {
    union { uint u; float f; } v{(uint)u << 16};
    return v.f;
}
__device__ inline uint4 pack8(float4 a, float4 b) {
    union { ushort us[8]; uint4 u4; } r;
    r.us[0]=f2bf(a.x); r.us[1]=f2bf(a.y); r.us[2]=f2bf(a.z); r.us[3]=f2bf(a.w);
    r.us[4]=f2bf(b.x); r.us[5]=f2bf(b.y); r.us[6]=f2bf(b.z); r.us[7]=f2bf(b.w);
    return r.u4;
}
// 128B-row LDS tiles (64 bf16): XOR-swizzle bank fix
__device__ inline int swz(int row, int kbyte) {
    return row * 128 + (kbyte ^ ((row & 7) << 4));
}
__device__ inline bf16x8 lds_frag(const ushort* base, int row, int kk, int lane) {
    int kbyte = kk * 64 + (lane >> 4) * 16;
    return *(const bf16x8*)((const char*)base + swz(row, kbyte));
}
// 512B-row LDS tiles (256 bf16): same XOR pattern
__device__ inline int swz512(int row, int kbyte) {
    return row * 512 + (kbyte ^ ((row & 7) << 4));
}
__device__ inline f32x4 mfma16(bf16x8 a, bf16x8 b, f32x4 c) {
    return __builtin_amdgcn_mfma_f32_16x16x32_bf16(a, b, c, 0, 0, 0);
}

// =====================================================================
// Wb (bf16) <- W fp32
// =====================================================================
__global__ __launch_bounds__(256) void wconv_kernel(
    const float* __restrict__ W, ushort* __restrict__ Wb)
{
    size_t i = ((size_t)blockIdx.x * 256 + threadIdx.x) * 8;
    float4 a = *(const float4*)(W + i);
    float4 b = *(const float4*)(W + i + 4);
    *(uint4*)(Wb + i) = pack8(a, b);
}

// =====================================================================
// gemmA (mega-staging): per block (b, s-tile of 64):
//   A-stage: qm = query*matrix fp32 -> bf16 (fused, no qm pass)
//   B-stage: ctx fp32 -> bf16; after MFMA, the staged B tile is ALSO
//            transpose-emitted to ctxT[b][d][s] (kills the ctxT kernel).
//   S = leaky(qm . ctx^T); col-l2norm over q (all 128 in-block);
//   E = exp(S*inv*smooth) bf16 -> global.  No softmax max-pass: |x|<=smooth.
// Grid 512 = (b x 4 s-tiles), XCD-swizzled. 512 thr, 8 waves 2q x 4s.
// BM=128 BN=64 BK=64, double-buffered LDS (48 KB).
// =====================================================================
__global__ __launch_bounds__(512) void gemmA_kernel(
    const float* __restrict__ query, const float* __restrict__ mat,
    const float* __restrict__ ctx, const int* __restrict__ smooth_p,
    ushort* __restrict__ E, ushort* __restrict__ ctxT)
{
    const int bid = blockIdx.x;
    const int xcd = bid & 7, idx = bid >> 3;
    const int b  = xcd * 16 + (idx >> 2);
    const int n0 = (idx & 3) * 64;        // s-offset
    __shared__ ushort As[2][128 * 64];
    __shared__ ushort Bs[2][64 * 64];
    __shared__ float colssP[2][64];
    __shared__ float invsm[64];
    const int t = threadIdx.x;
    const int wv = t >> 6, l = t & 63;
    const int wq = wv >> 2, wsv = wv & 3;

    const float* Qb = query + (size_t)b * LQ * D;
    const float* Mb = mat   + (size_t)b * LQ * D;
    const float* Cb = ctx   + ((size_t)b * LS + n0) * D;
    const int r0 = t >> 3, k8 = (t & 7) * 8;

    // ctxT transpose-emit coords: thread -> (d_local, 8 s-contig)
    const int ed = t >> 3;           // 0..63
    const int es = (t & 7) * 8;      // 0..56
    ushort* CTb = ctxT + (size_t)b * D * LS + n0 + es;

    f32x4 acc[4] = {};
    float4 q0, q1, q2, q3, m0, m1, m2, m3, c0, c1;

    // prologue: load + stage tile 0
    {
        const float* qp = Qb + (size_t)r0 * D + k8;
        const float* mp = Mb + (size_t)r0 * D + k8;
        q0 = *(const float4*)qp;  q1 = *(const float4*)(qp + 4);
        m0 = *(const float4*)mp;  m1 = *(const float4*)(mp + 4);
        qp += (size_t)64 * D;  mp += (size_t)64 * D;
        q2 = *(const float4*)qp;  q3 = *(const float4*)(qp + 4);
        m2 = *(const float4*)mp;  m3 = *(const float4*)(mp + 4);
        const float* cp = Cb + (size_t)r0 * D + k8;
        c0 = *(const float4*)cp;  c1 = *(const float4*)(cp + 4);
    }
    {
        float4 p1{q0.x*m0.x, q0.y*m0.y, q0.z*m0.z, q0.w*m0.w};
        float4 p2{q1.x*m1.x, q1.y*m1.y, q1.z*m1.z, q1.w*m1.w};
        *(uint4*)((char*)As[0] + swz(r0, k8 * 2)) = pack8(p1, p2);
        float4 p3{q2.x*m2.x, q2.y*m2.y, q2.z*m2.z, q2.w*m2.w};
        float4 p4{q3.x*m3.x, q3.y*m3.y, q3.z*m3.z, q3.w*m3.w};
        *(uint4*)((char*)As[0] + swz(r0 + 64, k8 * 2)) = pack8(p3, p4);
        *(uint4*)((char*)Bs[0] + swz(r0, k8 * 2)) = pack8(c0, c1);
    }
    __syncthreads();

    int cur = 0;
#pragma unroll 1
    for (int ks = 0; ks < 15; ++ks) {
        const int k0 = (ks + 1) * 64;
        // issue next-tile loads
        {
            const float* qp = Qb + (size_t)r0 * D + k0 + k8;
            const float* mp = Mb + (size_t)r0 * D + k0 + k8;
            q0 = *(const float4*)qp;  q1 = *(const float4*)(qp + 4);
            m0 = *(const float4*)mp;  m1 = *(const float4*)(mp + 4);
            qp += (size_t)64 * D;  mp += (size_t)64 * D;
            q2 = *(const float4*)qp;  q3 = *(const float4*)(qp + 4);
            m2 = *(const float4*)mp;  m3 = *(const float4*)(mp + 4);
            const float* cp = Cb + (size_t)r0 * D + k0 + k8;
            c0 = *(const float4*)cp;  c1 = *(const float4*)(cp + 4);
        }
        // MFMA on current buffer
#pragma unroll
        for (int kk = 0; kk < 2; ++kk) {
            bf16x8 bfr = lds_frag(Bs[cur], wsv * 16 + (l & 15), kk, l);
#pragma unroll
            for (int i = 0; i < 4; ++i) {
                bf16x8 af = lds_frag(As[cur], wq * 64 + i * 16 + (l & 15), kk, l);
                acc[i] = mfma16(af, bfr, acc[i]);
            }
        }
        // transpose-emit current B tile (d-range ks*64..) to ctxT
        {
            uint4 tv;
            ushort* tp = (ushort*)&tv;
#pragma unroll
            for (int j = 0; j < 8; ++j)
                tp[j] = *(const ushort*)((const char*)Bs[cur] + swz(es + j, ed * 2));
            *(uint4*)(CTb + (size_t)(ks * 64 + ed) * LS) = tv;
        }
        // stage next buffer
        {
            float4 p1{q0.x*m0.x, q0.y*m0.y, q0.z*m0.z, q0.w*m0.w};
            float4 p2{q1.x*m1.x, q1.y*m1.y, q1.z*m1.z, q1.w*m1.w};
            *(uint4*)((char*)As[cur ^ 1] + swz(r0, k8 * 2)) = pack8(p1, p2);
            float4 p3{q2.x*m2.x, q2.y*m2.y, q2.z*m2.z, q2.w*m2.w};
            float4 p4{q3.x*m3.x, q3.y*m3.y, q3.z*m3.z, q3.w*m3.w};
            *(uint4*)((char*)As[cur ^ 1] + swz(r0 + 64, k8 * 2)) = pack8(p3, p4);
            *(uint4*)((char*)Bs[cur ^ 1] + swz(r0, k8 * 2)) = pack8(c0, c1);
        }
        __syncthreads();
        cur ^= 1;
    }
    // final tile: MFMA + emit
#pragma unroll
    for (int kk = 0; kk < 2; ++kk) {
        bf16x8 bfr = lds_frag(Bs[cur], wsv * 16 + (l & 15), kk, l);
#pragma unroll
        for (int i = 0; i < 4; ++i) {
            bf16x8 af = lds_frag(As[cur], wq * 64 + i * 16 + (l & 15), kk, l);
            acc[i] = mfma16(af, bfr, acc[i]);
        }
    }
    {
        uint4 tv;
        ushort* tp = (ushort*)&tv;
#pragma unroll
        for (int j = 0; j < 8; ++j)
            tp[j] = *(const ushort*)((const char*)Bs[cur] + swz(es + j, ed * 2));
        *(uint4*)(CTb + (size_t)(15 * 64 + ed) * LS) = tv;
    }

    // epilogue: leaky + column sumsq (over all 128 q) -> invsm -> E=exp
    float csum = 0.f;
#pragma unroll
    for (int i = 0; i < 4; ++i)
#pragma unroll
        for (int r = 0; r < 4; ++r) {
            float v = acc[i][r];
            v = v >= 0.f ? v : 0.1f * v;
            acc[i][r] = v;
            csum += v * v;
        }
    csum += __shfl_xor(csum, 16);
    csum += __shfl_xor(csum, 32);
    if (l < 16) colssP[wq][wsv * 16 + l] = csum;
    __syncthreads();
    const float sm = (float)(*smooth_p);
    if (t < 64) invsm[t] = sm / (sqrtf(colssP[0][t] + colssP[1][t]) + EPS);
    __syncthreads();
    const float invc = invsm[wsv * 16 + (l & 15)];
    ushort* Eb = E + (size_t)b * LQ * LS + n0 + wsv * 16 + (l & 15);
#pragma unroll
    for (int i = 0; i < 4; ++i)
#pragma unroll
        for (int r = 0; r < 4; ++r) {
            int row = wq * 64 + i * 16 + (l >> 4) * 4 + r;
            Eb[(size_t)row * LS] = f2bf(__expf(acc[i][r] * invc));
        }
}

// =====================================================================
// pv: wctx[64q][512d] = (E . ctxT^T) * (1/rowsum(E)); rowss partials.
// Grid 512 = (b x 2 qh x 2 dh), XCD-swizzled. 512 thr, 8 waves 2q x 4d.
// =====================================================================
__global__ __launch_bounds__(512) void pv_kernel(
    const ushort* __restrict__ E, const ushort* __restrict__ ctxT,
    ushort* __restrict__ wctx, float* __restrict__ rowssP)
{
    const int bid = blockIdx.x;
    const int xcd = bid & 7, idx = bid >> 3;
    const int b  = xcd * 16 + (idx >> 2);
    const int qh = (idx >> 1) & 1, dh = idx & 1;
    __shared__ ushort Es[64 * 256];    // swz512
    __shared__ ushort Bs[64 * 256];    // swz512
    __shared__ float rsumL[64];
    __shared__ float rinv[64];
    __shared__ float rowssL[64][4];
    const int t = threadIdx.x;
    const int wv = t >> 6, l = t & 63;
    const int wq = wv >> 2, wd = wv & 3;
    const int cc = t & 31, rr = t >> 5;   // staging coords

    // stage E (64q x 256s) + per-row exp-sums
    const ushort* Eb = E + ((size_t)b * LQ + qh * 64) * LS;
    float part[4];
#pragma unroll
    for (int it = 0; it < 4; ++it) {
        int row = rr + it * 16;
        uint4 v = *(const uint4*)(Eb + (size_t)row * LS + cc * 8);
        *(uint4*)((char*)Es + swz512(row, cc * 16)) = v;
        const ushort* us = (const ushort*)&v;
        float s = 0.f;
#pragma unroll
        for (int j = 0; j < 8; ++j) s += bf2f(us[j]);
        part[it] = s;
    }
    if (t < 256) rowssL[t >> 2][t & 3] = 0.f;
#pragma unroll
    for (int it = 0; it < 4; ++it) {
        float s = part[it];
        s += __shfl_xor(s, 1);  s += __shfl_xor(s, 2);
        s += __shfl_xor(s, 4);  s += __shfl_xor(s, 8);
        s += __shfl_xor(s, 16);
        if ((l & 31) == 0) rsumL[rr + it * 16] = s;
    }
    __syncthreads();
    if (t < 64) rinv[t] = 1.0f / rsumL[t];
    __syncthreads();

    // hoist A-fragments (reused across all 8 d-tiles)
    bf16x8 af[2][8];
#pragma unroll
    for (int i = 0; i < 2; ++i)
#pragma unroll
        for (int kk = 0; kk < 8; ++kk)
            af[i][kk] = *(const bf16x8*)((const char*)Es +
                swz512(wq * 32 + i * 16 + (l & 15), kk * 64 + (l >> 4) * 16));

    const ushort* Cb = ctxT + ((size_t)b * D + dh * 512) * LS;
    ushort* Ob = wctx + ((size_t)b * LQ + qh * 64) * D + dh * 512;

#pragma unroll 1
    for (int dt = 0; dt < 8; ++dt) {
        __syncthreads();   // Bs free
#pragma unroll
        for (int it = 0; it < 4; ++it) {
            int row = rr + it * 16;
            uint4 v = *(const uint4*)(Cb + (size_t)(dt * 64 + row) * LS + cc * 8);
            *(uint4*)((char*)Bs + swz512(row, cc * 16)) = v;
        }
        __syncthreads();
        f32x4 acc[2] = {};
#pragma unroll
        for (int kk = 0; kk < 8; ++kk) {
            bf16x8 bfr = *(const bf16x8*)((const char*)Bs +
                swz512(wd * 16 + (l & 15), kk * 64 + (l >> 4) * 16));
            acc[0] = mfma16(af[0][kk], bfr, acc[0]);
            acc[1] = mfma16(af[1][kk], bfr, acc[1]);
        }
#pragma unroll
        for (int i = 0; i < 2; ++i)
#pragma unroll
            for (int r = 0; r < 4; ++r) {
                int row = wq * 32 + i * 16 + (l >> 4) * 4 + r;
                float wval = acc[i][r] * rinv[row];
                float p2 = wval * wval;
                p2 += __shfl_xor(p2, 1); p2 += __shfl_xor(p2, 2);
                p2 += __shfl_xor(p2, 4); p2 += __shfl_xor(p2, 8);
                if ((l & 15) == 0) rowssL[row][wd] += p2;
                Ob[(size_t)row * D + dt * 64 + wd * 16 + (l & 15)] = f2bf(wval);
            }
    }
    __syncthreads();
    if (t < 64)
        rowssP[(size_t)b * 256 + dh * 128 + qh * 64 + t] =
            rowssL[t][0] + rowssL[t][1] + rowssL[t][2] + rowssL[t][3];
}

// =====================================================================
// gemm3+finalnorm: out[b][q][k] = l2norm_k( sum_d sr[q][d]*Wb[k][d] + b[k] )
// sr on the fly: (query - wctx*invq)^2 with invq from rowssP halves.
// BM=64(q) BN=256 BK=64. 512 thr, 8 waves 2x4.
// =====================================================================
__global__ __launch_bounds__(512) void gemm3_kernel(
    const ushort* __restrict__ wctx, const float* __restrict__ query,
    const float* __restrict__ rowssP, const ushort* __restrict__ Wb,
    const float* __restrict__ bias, float* __restrict__ out)
{
    const int m0 = blockIdx.x * 64;
    const int b  = blockIdx.y;
    __shared__ ushort As[64 * 64];
    __shared__ ushort Bs[256 * 64];
    __shared__ float red[64][4];
    __shared__ float invr[64];
    const int t = threadIdx.x;
    const int w = t >> 6, l = t & 63;
    const int wm = (w >> 2) * 32, wn = (w & 3) * 64;

    const int arow = t >> 3, ako = (t & 7) * 8;
    const float r0v = rowssP[(size_t)b * 256 + m0 + arow];
    const float r1v = rowssP[(size_t)b * 256 + 128 + m0 + arow];
    const float ivq = 1.0f / (sqrtf(r0v + r1v) + EPS);
    const float* Qp  = query + ((size_t)b * LQ + m0 + arow) * D + ako;
    const ushort* Wp = wctx  + ((size_t)b * LQ + m0 + arow) * D + ako;

    f32x4 acc[2][4] = {};

    for (int k0 = 0; k0 < D; k0 += 64) {
        if (k0) __syncthreads();
        {   // A: sr on the fly
            uint4 wu = *(const uint4*)(Wp + k0);
            float4 q1 = *(const float4*)(Qp + k0);
            float4 q2 = *(const float4*)(Qp + k0 + 4);
            float d0 = q1.x - bf2f((ushort)(wu.x & 0xffff)) * ivq;
            float d1 = q1.y - bf2f((ushort)(wu.x >> 16))    * ivq;
            float d2 = q1.z - bf2f((ushort)(wu.y & 0xffff)) * ivq;
            float d3 = q1.w - bf2f((ushort)(wu.y >> 16))    * ivq;
            float d4 = q2.x - bf2f((ushort)(wu.z & 0xffff)) * ivq;
            float d5 = q2.y - bf2f((ushort)(wu.z >> 16))    * ivq;
            float d6 = q2.z - bf2f((ushort)(wu.w & 0xffff)) * ivq;
            float d7 = q2.w - bf2f((ushort)(wu.w >> 16))    * ivq;
            float4 s1{d0*d0, d1*d1, d2*d2, d3*d3};
            float4 s2{d4*d4, d5*d5, d6*d6, d7*d7};
            *(uint4*)((char*)As + swz(arow, ako * 2)) = pack8(s1, s2);
        }
#pragma unroll
        for (int j = 0; j < 4; ++j) {   // B: Wb
            int c = t + j * 512;
            int row = c >> 3, ko = (c & 7) * 8;
            *(uint4*)((char*)Bs + swz(row, ko * 2)) =
                *(const uint4*)(Wb + (size_t)row * D + k0 + ko);
        }
        __syncthreads();
#pragma unroll
        for (int kk = 0; kk < 2; ++kk) {
            bf16x8 af[2], bfr[4];
#pragma unroll
            for (int i = 0; i < 2; ++i) af[i] = lds_frag(As, wm + i * 16 + (l & 15), kk, l);
#pragma unroll
            for (int n = 0; n < 4; ++n) bfr[n] = lds_frag(Bs, wn + n * 16 + (l & 15), kk, l);
#pragma unroll
            for (int i = 0; i < 2; ++i)
#pragma unroll
                for (int n = 0; n < 4; ++n) acc[i][n] = mfma16(af[i], bfr[n], acc[i][n]);
        }
    }
#pragma unroll
    for (int n = 0; n < 4; ++n) {
        float bv = bias[wn + n * 16 + (l & 15)];
#pragma unroll
        for (int i = 0; i < 2; ++i)
#pragma unroll
            for (int r = 0; r < 4; ++r) acc[i][n][r] += bv;
    }
#pragma unroll
    for (int i = 0; i < 2; ++i)
#pragma unroll
        for (int r = 0; r < 4; ++r) {
            float p = 0.f;
#pragma unroll
            for (int n = 0; n < 4; ++n) p += acc[i][n][r] * acc[i][n][r];
#pragma unroll
            for (int off = 1; off < 16; off <<= 1) p += __shfl_xor(p, off);
            int rowl = wm + i * 16 + (l >> 4) * 4 + r;
            if ((l & 15) == 0) red[rowl][w & 3] = p;
        }
    __syncthreads();
    if (t < 64) {
        float s = red[t][0] + red[t][1] + red[t][2] + red[t][3];
        invr[t] = 1.0f / (sqrtf(s) + EPS);
    }
    __syncthreads();
    float* Ob = out + ((size_t)b * LQ + m0) * SD;
#pragma unroll
    for (int i = 0; i < 2; ++i)
#pragma unroll
        for (int r = 0; r < 4; ++r) {
            int rowl = wm + i * 16 + (l >> 4) * 4 + r;
            float iv = invr[rowl];
#pragma unroll
            for (int n = 0; n < 4; ++n) {
                int col = wn + n * 16 + (l & 15);
                Ob[(size_t)rowl * SD + col] = acc[i][n][r] * iv;
            }
        }
}

// =====================================================================
extern "C" void kernel_launch(void* const* d_in, const int* in_sizes, int n_in,
                              void* d_out, int out_size, void* d_ws, size_t ws_size,
                              hipStream_t stream)
{
    const float* query  = (const float*)d_in[0];
    const float* ctx    = (const float*)d_in[1];
    const float* mat    = (const float*)d_in[2];
    const float* W      = (const float*)d_in[3];
    const float* bias   = (const float*)d_in[4];
    const int*   smooth = (const int*)d_in[5];
    float* out = (float*)d_out;

    char* ws = (char*)d_ws;
    ushort* ctxT   = (ushort*)ws;                                   // 64 MiB
    ushort* wctx   = (ushort*)(ws + (size_t)64 * 1024 * 1024);      // 32 MiB
    ushort* E      = (ushort*)(ws + (size_t)96 * 1024 * 1024);      //  8 MiB
    ushort* Wb     = (ushort*)(ws + (size_t)104 * 1024 * 1024);     // 0.5 MiB
    float*  rowssP = (float*)(ws + (size_t)(104 * 1024 + 512) * 1024); // 128 KiB

    wconv_kernel<<<dim3(SD * D / (256 * 8)), 256, 0, stream>>>(W, Wb);
    gemmA_kernel<<<dim3(512), 512, 0, stream>>>(query, mat, ctx, smooth, E, ctxT);
    pv_kernel<<<dim3(512), 512, 0, stream>>>(E, ctxT, wctx, rowssP);
    gemm3_kernel<<<dim3(2, B), 512, 0, stream>>>(wctx, query, rowssP, Wb, bias, out);
}

// Round 8
// 156.309 us; speedup vs baseline: 3.2068x; 1.0415x over previous
//
#include <hip/hip_runtime.h>
#include <hip/hip_bf16.h>

constexpr int B  = 128;
constexpr int LQ = 128;
constexpr int LS = 256;
constexpr int D  = 1024;
constexpr int SD = 256;
constexpr float EPS = 1e-8f;

typedef __attribute__((ext_vector_type(8))) __bf16 bf16x8;
typedef __attribute__((ext_vector_type(4))) float f32x4;

__device__ inline ushort f2bf(float f) {
    union { float f; uint u; } v{f};
    uint r = v.u + 0x7fffu + ((v.u >> 16) & 1u);   // RNE
    return (ushort)(r >> 16);
}
__device__ inline float bf2f(ushort u) {
    union { uint u; float f; } v{(uint)u << 16};
    return v.f;
}
__device__ inline uint4 pack8(float4 a, float4 b) {
    union { ushort us[8]; uint4 u4; } r;
    r.us[0]=f2bf(a.x); r.us[1]=f2bf(a.y); r.us[2]=f2bf(a.z); r.us[3]=f2bf(a.w);
    r.us[4]=f2bf(b.x); r.us[5]=f2bf(b.y); r.us[6]=f2bf(b.z); r.us[7]=f2bf(b.w);
    return r.u4;
}
// 128B-row LDS tiles (64 bf16): XOR-swizzle bank fix
__device__ inline int swz(int row, int kbyte) {
    return row * 128 + (kbyte ^ ((row & 7) << 4));
}
__device__ inline bf16x8 lds_frag(const ushort* base, int row, int kk, int lane) {
    int kbyte = kk * 64 + (lane >> 4) * 16;
    return *(const bf16x8*)((const char*)base + swz(row, kbyte));
}
// 512B-row LDS tiles (256 bf16): same XOR pattern
__device__ inline int swz512(int row, int kbyte) {
    return row * 512 + (kbyte ^ ((row & 7) << 4));
}
__device__ inline f32x4 mfma16(bf16x8 a, bf16x8 b, f32x4 c) {
    return __builtin_amdgcn_mfma_f32_16x16x32_bf16(a, b, c, 0, 0, 0);
}

// =====================================================================
// Wb (bf16) <- W fp32
// =====================================================================
__global__ __launch_bounds__(256) void wconv_kernel(
    const float* __restrict__ W, ushort* __restrict__ Wb)
{
    size_t i = ((size_t)blockIdx.x * 256 + threadIdx.x) * 8;
    float4 a = *(const float4*)(W + i);
    float4 b = *(const float4*)(W + i + 4);
    *(uint4*)(Wb + i) = pack8(a, b);
}

// =====================================================================
// gemmA: per block (b, s-tile of 64):
//   A-stage: qm = query*matrix fp32 -> bf16 (fused)
//   S = leaky(qm . ctx^T); col-l2norm over q (all 128 in-block);
//   E = exp(S*inv*smooth) bf16 -> global.  No softmax max-pass: |x|<=smooth.
// Grid 512 = (b x 4 s-tiles), XCD-swizzled. 512 thr, 8 waves 2q x 4s.
// BM=128 BN=64 BK=64, double-buffered LDS (48 KB).
// =====================================================================
__global__ __launch_bounds__(512) void gemmA_kernel(
    const float* __restrict__ query, const float* __restrict__ mat,
    const float* __restrict__ ctx, const int* __restrict__ smooth_p,
    ushort* __restrict__ E)
{
    const int bid = blockIdx.x;
    const int xcd = bid & 7, idx = bid >> 3;
    const int b  = xcd * 16 + (idx >> 2);
    const int n0 = (idx & 3) * 64;        // s-offset
    __shared__ ushort As[2][128 * 64];
    __shared__ ushort Bs[2][64 * 64];
    __shared__ float colssP[2][64];
    __shared__ float invsm[64];
    const int t = threadIdx.x;
    const int wv = t >> 6, l = t & 63;
    const int wq = wv >> 2, wsv = wv & 3;

    const float* Qb = query + (size_t)b * LQ * D;
    const float* Mb = mat   + (size_t)b * LQ * D;
    const float* Cb = ctx   + ((size_t)b * LS + n0) * D;
    const int r0 = t >> 3, k8 = (t & 7) * 8;

    f32x4 acc[4] = {};
    float4 q0, q1, q2, q3, m0, m1, m2, m3, c0, c1;

    // prologue: load + stage tile 0
    {
        const float* qp = Qb + (size_t)r0 * D + k8;
        const float* mp = Mb + (size_t)r0 * D + k8;
        q0 = *(const float4*)qp;  q1 = *(const float4*)(qp + 4);
        m0 = *(const float4*)mp;  m1 = *(const float4*)(mp + 4);
        qp += (size_t)64 * D;  mp += (size_t)64 * D;
        q2 = *(const float4*)qp;  q3 = *(const float4*)(qp + 4);
        m2 = *(const float4*)mp;  m3 = *(const float4*)(mp + 4);
        const float* cp = Cb + (size_t)r0 * D + k8;
        c0 = *(const float4*)cp;  c1 = *(const float4*)(cp + 4);
    }
    {
        float4 p1{q0.x*m0.x, q0.y*m0.y, q0.z*m0.z, q0.w*m0.w};
        float4 p2{q1.x*m1.x, q1.y*m1.y, q1.z*m1.z, q1.w*m1.w};
        *(uint4*)((char*)As[0] + swz(r0, k8 * 2)) = pack8(p1, p2);
        float4 p3{q2.x*m2.x, q2.y*m2.y, q2.z*m2.z, q2.w*m2.w};
        float4 p4{q3.x*m3.x, q3.y*m3.y, q3.z*m3.z, q3.w*m3.w};
        *(uint4*)((char*)As[0] + swz(r0 + 64, k8 * 2)) = pack8(p3, p4);
        *(uint4*)((char*)Bs[0] + swz(r0, k8 * 2)) = pack8(c0, c1);
    }
    __syncthreads();

    int cur = 0;
#pragma unroll 1
    for (int ks = 0; ks < 15; ++ks) {
        const int k0 = (ks + 1) * 64;
        // issue next-tile loads
        {
            const float* qp = Qb + (size_t)r0 * D + k0 + k8;
            const float* mp = Mb + (size_t)r0 * D + k0 + k8;
            q0 = *(const float4*)qp;  q1 = *(const float4*)(qp + 4);
            m0 = *(const float4*)mp;  m1 = *(const float4*)(mp + 4);
            qp += (size_t)64 * D;  mp += (size_t)64 * D;
            q2 = *(const float4*)qp;  q3 = *(const float4*)(qp + 4);
            m2 = *(const float4*)mp;  m3 = *(const float4*)(mp + 4);
            const float* cp = Cb + (size_t)r0 * D + k0 + k8;
            c0 = *(const float4*)cp;  c1 = *(const float4*)(cp + 4);
        }
        // MFMA on current buffer
#pragma unroll
        for (int kk = 0; kk < 2; ++kk) {
            bf16x8 bfr = lds_frag(Bs[cur], wsv * 16 + (l & 15), kk, l);
#pragma unroll
            for (int i = 0; i < 4; ++i) {
                bf16x8 af = lds_frag(As[cur], wq * 64 + i * 16 + (l & 15), kk, l);
                acc[i] = mfma16(af, bfr, acc[i]);
            }
        }
        // stage next buffer
        {
            float4 p1{q0.x*m0.x, q0.y*m0.y, q0.z*m0.z, q0.w*m0.w};
            float4 p2{q1.x*m1.x, q1.y*m1.y, q1.z*m1.z, q1.w*m1.w};
            *(uint4*)((char*)As[cur ^ 1] + swz(r0, k8 * 2)) = pack8(p1, p2);
            float4 p3{q2.x*m2.x, q2.y*m2.y, q2.z*m2.z, q2.w*m2.w};
            float4 p4{q3.x*m3.x, q3.y*m3.y, q3.z*m3.z, q3.w*m3.w};
            *(uint4*)((char*)As[cur ^ 1] + swz(r0 + 64, k8 * 2)) = pack8(p3, p4);
            *(uint4*)((char*)Bs[cur ^ 1] + swz(r0, k8 * 2)) = pack8(c0, c1);
        }
        __syncthreads();
        cur ^= 1;
    }
    // final tile: MFMA
#pragma unroll
    for (int kk = 0; kk < 2; ++kk) {
        bf16x8 bfr = lds_frag(Bs[cur], wsv * 16 + (l & 15), kk, l);
#pragma unroll
        for (int i = 0; i < 4; ++i) {
            bf16x8 af = lds_frag(As[cur], wq * 64 + i * 16 + (l & 15), kk, l);
            acc[i] = mfma16(af, bfr, acc[i]);
        }
    }

    // epilogue: leaky + column sumsq (over all 128 q) -> invsm -> E=exp
    float csum = 0.f;
#pragma unroll
    for (int i = 0; i < 4; ++i)
#pragma unroll
        for (int r = 0; r < 4; ++r) {
            float v = acc[i][r];
            v = v >= 0.f ? v : 0.1f * v;
            acc[i][r] = v;
            csum += v * v;
        }
    csum += __shfl_xor(csum, 16);
    csum += __shfl_xor(csum, 32);
    if (l < 16) colssP[wq][wsv * 16 + l] = csum;
    __syncthreads();
    const float sm = (float)(*smooth_p);
    if (t < 64) invsm[t] = sm / (sqrtf(colssP[0][t] + colssP[1][t]) + EPS);
    __syncthreads();
    const float invc = invsm[wsv * 16 + (l & 15)];
    ushort* Eb = E + (size_t)b * LQ * LS + n0 + wsv * 16 + (l & 15);
#pragma unroll
    for (int i = 0; i < 4; ++i)
#pragma unroll
        for (int r = 0; r < 4; ++r) {
            int row = wq * 64 + i * 16 + (l >> 4) * 4 + r;
            Eb[(size_t)row * LS] = f2bf(__expf(acc[i][r] * invc));
        }
}

// =====================================================================
// pv: wctx[128q][512d-half] = (E . ctx^T) * (1/rowsum(E)); rowss partials.
// Grid 256 = (b x 2 dh), XCD-swizzled. 512 thr, 8 waves 2q x 4d.
// B-operand staged DIRECTLY from fp32 ctx[s][d] via in-LDS transpose
// into padded Bs[64][264] (no ctxT global tensor). Reg-prefetch per dt.
// =====================================================================
__global__ __launch_bounds__(512) void pv_kernel(
    const ushort* __restrict__ E, const float* __restrict__ ctx,
    ushort* __restrict__ wctx, float* __restrict__ rowssP)
{
    const int bid = blockIdx.x;
    const int xcd = bid & 7, idx = bid >> 3;
    const int b  = xcd * 16 + (idx >> 1);
    const int dh = idx & 1;
    const int dglob0 = dh * 512;

    __shared__ ushort Es[128 * 256];       // 64 KB swz512
    __shared__ ushort Bs[64 * 264];        // 33 KB padded [d][s+8]
    __shared__ float rsumL[128];
    __shared__ float rinv[128];
    __shared__ float rowssL[128][4];

    const int t = threadIdx.x;
    const int wv = t >> 6, l = t & 63;
    const int wq = wv >> 2, wd = wv & 3;

    // ---- stage E (128q x 256s) + per-row exp sums ----
    const ushort* Eb = E + (size_t)b * LQ * LS;
    const int cc = t & 31, rr = t >> 5;    // col-chunk, row-base
    float part[8];
#pragma unroll
    for (int p = 0; p < 8; ++p) {
        int row = rr + p * 16;
        uint4 v = *(const uint4*)(Eb + (size_t)row * LS + cc * 8);
        *(uint4*)((char*)Es + swz512(row, cc * 16)) = v;
        const ushort* us = (const ushort*)&v;
        float s = 0.f;
#pragma unroll
        for (int j = 0; j < 8; ++j) s += bf2f(us[j]);
        part[p] = s;
    }
    rowssL[t >> 2][t & 3] = 0.f;
#pragma unroll
    for (int p = 0; p < 8; ++p) {
        float s = part[p];
        s += __shfl_xor(s, 1);  s += __shfl_xor(s, 2);
        s += __shfl_xor(s, 4);  s += __shfl_xor(s, 8);
        s += __shfl_xor(s, 16);
        if ((l & 31) == 0) rsumL[rr + p * 16] = s;
    }

    // ---- prefetch ctx tile dt=0 (coalesced float4 rows) ----
    const float* Cb = ctx + (size_t)b * LS * D + dglob0;
    const int sr = t >> 4, c4 = (t & 15) * 4;   // staging: s-row base, d-col
    float4 cr[8];
#pragma unroll
    for (int p = 0; p < 8; ++p)
        cr[p] = *(const float4*)(Cb + (size_t)(p * 32 + sr) * D + c4);

    __syncthreads();   // Es + rsumL visible
    if (t < 128) rinv[t] = 1.0f / rsumL[t];

    // ---- write Bs dt=0 (transpose scatter into padded tile) ----
#pragma unroll
    for (int p = 0; p < 8; ++p) {
        int s = p * 32 + sr;
        Bs[(c4 + 0) * 264 + s] = f2bf(cr[p].x);
        Bs[(c4 + 1) * 264 + s] = f2bf(cr[p].y);
        Bs[(c4 + 2) * 264 + s] = f2bf(cr[p].z);
        Bs[(c4 + 3) * 264 + s] = f2bf(cr[p].w);
    }
    __syncthreads();   // Bs + rinv visible

    ushort* Ob = wctx + (size_t)b * LQ * D + dglob0;

#pragma unroll 1
    for (int dt = 0; dt < 8; ++dt) {
        // issue next-tile loads (hide under MFMA)
        if (dt < 7) {
#pragma unroll
            for (int p = 0; p < 8; ++p)
                cr[p] = *(const float4*)(Cb + (size_t)(p * 32 + sr) * D + (dt + 1) * 64 + c4);
        }
        // MFMA: out rows wq*64+i*16.., cols dt*64 + wd*16..
        f32x4 acc[4] = {};
#pragma unroll
        for (int kk = 0; kk < 8; ++kk) {
            const ushort* bp = Bs + (wd * 16 + (l & 15)) * 264 + kk * 32 + (l >> 4) * 8;
            bf16x8 bfr = *(const bf16x8*)bp;
#pragma unroll
            for (int i = 0; i < 4; ++i) {
                bf16x8 af = *(const bf16x8*)((const char*)Es +
                    swz512(wq * 64 + i * 16 + (l & 15), kk * 64 + (l >> 4) * 16));
                acc[i] = mfma16(af, bfr, acc[i]);
            }
        }
        // epilogue: normalize, rowss partial, write
#pragma unroll
        for (int i = 0; i < 4; ++i)
#pragma unroll
            for (int r = 0; r < 4; ++r) {
                int row = wq * 64 + i * 16 + (l >> 4) * 4 + r;
                float wval = acc[i][r] * rinv[row];
                float p2 = wval * wval;
                p2 += __shfl_xor(p2, 1); p2 += __shfl_xor(p2, 2);
                p2 += __shfl_xor(p2, 4); p2 += __shfl_xor(p2, 8);
                if ((l & 15) == 0) rowssL[row][wd] += p2;
                Ob[(size_t)row * D + dt * 64 + wd * 16 + (l & 15)] = f2bf(wval);
            }
        __syncthreads();   // Bs consumed
        if (dt < 7) {
#pragma unroll
            for (int p = 0; p < 8; ++p) {
                int s = p * 32 + sr;
                Bs[(c4 + 0) * 264 + s] = f2bf(cr[p].x);
                Bs[(c4 + 1) * 264 + s] = f2bf(cr[p].y);
                Bs[(c4 + 2) * 264 + s] = f2bf(cr[p].z);
                Bs[(c4 + 3) * 264 + s] = f2bf(cr[p].w);
            }
            __syncthreads();
        }
    }
    if (t < 128)
        rowssP[(size_t)b * 256 + dh * 128 + t] =
            rowssL[t][0] + rowssL[t][1] + rowssL[t][2] + rowssL[t][3];
}

// =====================================================================
// gemm3+finalnorm: out[b][q][k] = l2norm_k( sum_d sr[q][d]*Wb[k][d] + b[k] )
// sr on the fly: (query - wctx*invq)^2 with invq from rowssP halves.
// BM=64(q) BN=256 BK=64. 512 thr, 8 waves 2x4.
// =====================================================================
__global__ __launch_bounds__(512) void gemm3_kernel(
    const ushort* __restrict__ wctx, const float* __restrict__ query,
    const float* __restrict__ rowssP, const ushort* __restrict__ Wb,
    const float* __restrict__ bias, float* __restrict__ out)
{
    const int m0 = blockIdx.x * 64;
    const int b  = blockIdx.y;
    __shared__ ushort As[64 * 64];
    __shared__ ushort Bs[256 * 64];
    __shared__ float red[64][4];
    __shared__ float invr[64];
    const int t = threadIdx.x;
    const int w = t >> 6, l = t & 63;
    const int wm = (w >> 2) * 32, wn = (w & 3) * 64;

    const int arow = t >> 3, ako = (t & 7) * 8;
    const float r0v = rowssP[(size_t)b * 256 + m0 + arow];
    const float r1v = rowssP[(size_t)b * 256 + 128 + m0 + arow];
    const float ivq = 1.0f / (sqrtf(r0v + r1v) + EPS);
    const float* Qp  = query + ((size_t)b * LQ + m0 + arow) * D + ako;
    const ushort* Wp = wctx  + ((size_t)b * LQ + m0 + arow) * D + ako;

    f32x4 acc[2][4] = {};

    for (int k0 = 0; k0 < D; k0 += 64) {
        if (k0) __syncthreads();
        {   // A: sr on the fly
            uint4 wu = *(const uint4*)(Wp + k0);
            float4 q1 = *(const float4*)(Qp + k0);
            float4 q2 = *(const float4*)(Qp + k0 + 4);
            float d0 = q1.x - bf2f((ushort)(wu.x & 0xffff)) * ivq;
            float d1 = q1.y - bf2f((ushort)(wu.x >> 16))    * ivq;
            float d2 = q1.z - bf2f((ushort)(wu.y & 0xffff)) * ivq;
            float d3 = q1.w - bf2f((ushort)(wu.y >> 16))    * ivq;
            float d4 = q2.x - bf2f((ushort)(wu.z & 0xffff)) * ivq;
            float d5 = q2.y - bf2f((ushort)(wu.z >> 16))    * ivq;
            float d6 = q2.z - bf2f((ushort)(wu.w & 0xffff)) * ivq;
            float d7 = q2.w - bf2f((ushort)(wu.w >> 16))    * ivq;
            float4 s1{d0*d0, d1*d1, d2*d2, d3*d3};
            float4 s2{d4*d4, d5*d5, d6*d6, d7*d7};
            *(uint4*)((char*)As + swz(arow, ako * 2)) = pack8(s1, s2);
        }
#pragma unroll
        for (int j = 0; j < 4; ++j) {   // B: Wb
            int c = t + j * 512;
            int row = c >> 3, ko = (c & 7) * 8;
            *(uint4*)((char*)Bs + swz(row, ko * 2)) =
                *(const uint4*)(Wb + (size_t)row * D + k0 + ko);
        }
        __syncthreads();
#pragma unroll
        for (int kk = 0; kk < 2; ++kk) {
            bf16x8 af[2], bfr[4];
#pragma unroll
            for (int i = 0; i < 2; ++i) af[i] = lds_frag(As, wm + i * 16 + (l & 15), kk, l);
#pragma unroll
            for (int n = 0; n < 4; ++n) bfr[n] = lds_frag(Bs, wn + n * 16 + (l & 15), kk, l);
#pragma unroll
            for (int i = 0; i < 2; ++i)
#pragma unroll
                for (int n = 0; n < 4; ++n) acc[i][n] = mfma16(af[i], bfr[n], acc[i][n]);
        }
    }
#pragma unroll
    for (int n = 0; n < 4; ++n) {
        float bv = bias[wn + n * 16 + (l & 15)];
#pragma unroll
        for (int i = 0; i < 2; ++i)
#pragma unroll
            for (int r = 0; r < 4; ++r) acc[i][n][r] += bv;
    }
#pragma unroll
    for (int i = 0; i < 2; ++i)
#pragma unroll
        for (int r = 0; r < 4; ++r) {
            float p = 0.f;
#pragma unroll
            for (int n = 0; n < 4; ++n) p += acc[i][n][r] * acc[i][n][r];
#pragma unroll
            for (int off = 1; off < 16; off <<= 1) p += __shfl_xor(p, off);
            int rowl = wm + i * 16 + (l >> 4) * 4 + r;
            if ((l & 15) == 0) red[rowl][w & 3] = p;
        }
    __syncthreads();
    if (t < 64) {
        float s = red[t][0] + red[t][1] + red[t][2] + red[t][3];
        invr[t] = 1.0f / (sqrtf(s) + EPS);
    }
    __syncthreads();
    float* Ob = out + ((size_t)b * LQ + m0) * SD;
#pragma unroll
    for (int i = 0; i < 2; ++i)
#pragma unroll
        for (int r = 0; r < 4; ++r) {
            int rowl = wm + i * 16 + (l >> 4) * 4 + r;
            float iv = invr[rowl];
#pragma unroll
            for (int n = 0; n < 4; ++n) {
                int col = wn + n * 16 + (l & 15);
                Ob[(size_t)rowl * SD + col] = acc[i][n][r] * iv;
            }
        }
}

// =====================================================================
extern "C" void kernel_launch(void* const* d_in, const int* in_sizes, int n_in,
                              void* d_out, int out_size, void* d_ws, size_t ws_size,
                              hipStream_t stream)
{
    const float* query  = (const float*)d_in[0];
    const float* ctx    = (const float*)d_in[1];
    const float* mat    = (const float*)d_in[2];
    const float* W      = (const float*)d_in[3];
    const float* bias   = (const float*)d_in[4];
    const int*   smooth = (const int*)d_in[5];
    float* out = (float*)d_out;

    char* ws = (char*)d_ws;
    ushort* wctx   = (ushort*)ws;                                   // 32 MiB
    ushort* E      = (ushort*)(ws + (size_t)32 * 1024 * 1024);      //  8 MiB
    ushort* Wb     = (ushort*)(ws + (size_t)40 * 1024 * 1024);      // 0.5 MiB
    float*  rowssP = (float*)(ws + (size_t)(40 * 1024 + 512) * 1024); // 128 KiB

    wconv_kernel<<<dim3(SD * D / (256 * 8)), 256, 0, stream>>>(W, Wb);
    gemmA_kernel<<<dim3(512), 512, 0, stream>>>(query, mat, ctx, smooth, E);
    pv_kernel<<<dim3(256), 512, 0, stream>>>(E, ctx, wctx, rowssP);
    gemm3_kernel<<<dim3(2, B), 512, 0, stream>>>(wctx, query, rowssP, Wb, bias, out);
}